// Round 11
// baseline (306.384 us; speedup 1.0000x reference)
//
#include <hip/hip_runtime.h>
#include <stdint.h>

// Problem: B=4, S=2048, D=1024, H=16, HD=64. I/O fp32; internal compute bf16
// MFMA with fp32 accumulation.
// SCALE*log2(e) folded into wq^T and bq -> flash uses exp2 directly with a
// FIXED softmax max of 0 (shift-invariant; logits statically bounded ~|9|).
// Flash lineage: R9 99.7 -> R15 T14 async reg-staging 93.7 (-12% CONFIRMED);
// R13/R14/R16/R17 structural nulls => flash at structure floor, FROZEN.
// R18: gemm launch_bounds (256,2)->(256,3) NULL => occupancy wasn't binding.
// Ledger (stable over R17/R18): gemms ~162us for 68.7GF ~= 425 TF.
// R19 (this round): gemm<0> -> 256x256/BK=64 tile, 2-phase issue-early dbuf
// (the race-free T3-minimum recipe; same transformation that won R15):
//   stage(kt+1 -> buf^1) issued BEFORE compute(kt on buf); ONE
//   __syncthreads() per K-tile (drains vmcnt => kt+1 landed, fences switch).
// 16x fewer barrier events per FLOP vs m97 structure. 512 thr / 8 waves
// (2Mx4N), per-wave 128x64 (acc[8][4]), LDS 128KB, grid 384 XCD-bijective.
// No LDS swizzle (T2 null at 2-phase, m252). gemm<1> stays on old 128^2
// kernel (N=1024 would give only 128 blocks at 256^2). Flash frozen.

typedef __attribute__((ext_vector_type(8))) short bf16x8;
typedef __attribute__((ext_vector_type(4))) short bf16x4;
typedef __attribute__((ext_vector_type(4))) float f32x4;
typedef __attribute__((ext_vector_type(16))) float f32x16;
typedef __attribute__((ext_vector_type(4))) int i32x4;
typedef unsigned short u16;
typedef unsigned int u32;

#define AS1 __attribute__((address_space(1)))
#define AS3 __attribute__((address_space(3)))

#define SCALE_L2E 0.18033688011112042f  // 0.125 * log2(e)

__device__ __forceinline__ void gld_lds16(const void* g, void* l) {
  // async global->LDS DMA: lane i's 16B land at (wave-uniform) l + i*16
  __builtin_amdgcn_global_load_lds((const AS1 void*)g, (AS3 void*)l, 16, 0, 0);
}

__device__ __forceinline__ u16 f2bf(float f) {
  u32 x = __builtin_bit_cast(u32, f);
  x += 0x7fff + ((x >> 16) & 1);  // RNE
  return (u16)(x >> 16);
}

__device__ __forceinline__ u16 f2bf_fast(float a) {
#if __has_builtin(__builtin_amdgcn_cvt_pk_bf16_f32)
  auto v = __builtin_amdgcn_cvt_pk_bf16_f32(a, a);  // both halves = a: order-immune
  return (u16)(__builtin_bit_cast(u32, v) & 0xffffu);
#else
  return f2bf(a);
#endif
}

__device__ __forceinline__ u32 pk2(float a, float b) {  // lo16=a, hi16=b
#if __has_builtin(__builtin_amdgcn_cvt_pk_bf16_f32)
  return __builtin_bit_cast(u32, __builtin_amdgcn_cvt_pk_bf16_f32(a, b));
#else
  return (u32)f2bf(a) | ((u32)f2bf(b) << 16);
#endif
}

__device__ __forceinline__ float exp2_fast(float x) {
#if __has_builtin(__builtin_amdgcn_exp2f)
  return __builtin_amdgcn_exp2f(x);
#else
  return exp2f(x);
#endif
}

__device__ __forceinline__ f32x16 zero16() {
  f32x16 z;
#pragma unroll
  for (int i = 0; i < 16; ++i) z[i] = 0.f;
  return z;
}

// ---------------------------------------------------------------------------
// fp32 -> bf16 conversion of x (8M elements)
// ---------------------------------------------------------------------------
__global__ __launch_bounds__(256) void convert_x(const float* __restrict__ x,
                                                 u16* __restrict__ xb) {
  int i = (blockIdx.x * 256 + threadIdx.x) * 4;
  float4 v = *(const float4*)(x + i);
  ushort4 o;
  o.x = f2bf(v.x); o.y = f2bf(v.y); o.z = f2bf(v.z); o.w = f2bf(v.w);
  *(ushort4*)(xb + i) = o;
}

// ---------------------------------------------------------------------------
// Weight pack (fp32 [K][N] -> bf16 [N][K]); wq scaled by SCALE*log2(e)
// ---------------------------------------------------------------------------
__global__ __launch_bounds__(256) void pack_weights(
    const float* __restrict__ wq, const float* __restrict__ wk,
    const float* __restrict__ wv, const float* __restrict__ wo,
    u16* __restrict__ wt_qkv, u16* __restrict__ wt_o) {
  __shared__ float tile[64][65];
  int mat = blockIdx.z;
  const float* src = (mat == 0) ? wq : (mat == 1) ? wk : (mat == 2) ? wv : wo;
  int k0 = blockIdx.y * 64, j0 = blockIdx.x * 64;
  int t = threadIdx.x;
  int lr = t >> 6;   // 0..3
  int lc = t & 63;
#pragma unroll
  for (int it = 0; it < 16; ++it) {
    int r = it * 4 + lr;
    tile[r][lc] = src[(size_t)(k0 + r) * 1024 + j0 + lc];
  }
  __syncthreads();
  u16* dst = (mat == 3) ? wt_o : (wt_qkv + (size_t)mat * 1024 * 1024);
#pragma unroll
  for (int it = 0; it < 16; ++it) {
    int nl = it * 4 + lr;
    float v = tile[lc][nl];
    if (mat == 0) v *= SCALE_L2E;  // fold attention scale + log2(e)
    dst[(size_t)(j0 + nl) * 1024 + k0 + lc] = f2bf(v);
  }
}

// ---------------------------------------------------------------------------
// gemm256_qkv (R19): fused QKV GEMM, 256x256 tile, BK=64, 2-phase dbuf.
// C[M,3072] = A[M,1024] x Bt[3072,1024]^T + bias. 512 thr = 8 waves (2Mx4N);
// per-wave 128x64 out = acc[8][4] of 16x16 frags. LDS 2 bufs x (A,B) 32KB.
// Per K-tile: issue 8 gload_lds for kt+1 -> buf^1; compute buf (2 ks x
// {8 A-frag + 4 B-frag ds_read_b128, 32 MFMA}); __syncthreads (drain+fence).
// Race-free: stages always target the not-being-read buffer; barrier at
// iteration end retires them before first read.
// Grid 384: xcd=bid&7 owns m-tiles [xcd*4,+4) x all 12 n-tiles (bijective).
// Epilogue: mat uniform per block (BN=256 divides 1024).
//   Q,K row-major bf16; V fragment-direct image (same formula as R17).
// ---------------------------------------------------------------------------
__global__ __launch_bounds__(512, 2) void gemm256_qkv(
    const u16* __restrict__ A, const u16* __restrict__ Bt,
    const float* __restrict__ bias0, const float* __restrict__ bias1,
    const float* __restrict__ bias2,
    u16* __restrict__ outQ, u16* __restrict__ outK, u16* __restrict__ outV) {
  __shared__ u16 lA[2][256 * 64];  // [buf][m][k] rows of 64 bf16 (32KB each)
  __shared__ u16 lB[2][256 * 64];  // [buf][n][k]
  int tid = threadIdx.x;
  int wave = tid >> 6, lane = tid & 63;
  int wr = wave >> 2, wc = wave & 3;  // 2M x 4N wave grid

  int bid = blockIdx.x;
  int xcd = bid & 7, j = bid >> 3;          // j 0..47
  int m0 = (xcd * 4 + (j & 3)) * 256;       // m-tiles 0..31 (bijective)
  int n0 = (j >> 2) * 256;                  // n-tiles 0..11

  f32x4 acc[8][4];
#pragma unroll
  for (int fm = 0; fm < 8; ++fm)
#pragma unroll
    for (int fn = 0; fn < 4; ++fn) acc[fm][fn] = f32x4{0.f, 0.f, 0.f, 0.f};

  int srow = lane >> 3;        // staging: 8 rows per wave per issue
  int scol = (lane & 7) * 8;   // 8 bf16 = 16B per lane
  int fr = lane & 15;          // fragment row-within-16 / epilogue col
  int kq = (lane >> 4) * 8;    // fragment k-offset within 32-chunk

  // prologue: stage K-tile 0 into buf 0 (8 DMAs), drain, fence
#pragma unroll
  for (int seg = 0; seg < 4; ++seg) {
    int r0 = seg * 64 + wave * 8;
    gld_lds16(A + (size_t)(m0 + r0 + srow) * 1024 + scol, &lA[0][r0 * 64]);
    gld_lds16(Bt + (size_t)(n0 + r0 + srow) * 1024 + scol, &lB[0][r0 * 64]);
  }
  __syncthreads();

  int cur = 0;
  for (int kt = 0; kt < 16; ++kt) {
    if (kt < 15) {  // issue next-tile stages; they land under compute
      int k1 = (kt + 1) * 64;
#pragma unroll
      for (int seg = 0; seg < 4; ++seg) {
        int r0 = seg * 64 + wave * 8;
        gld_lds16(A + (size_t)(m0 + r0 + srow) * 1024 + k1 + scol,
                  &lA[cur ^ 1][r0 * 64]);
        gld_lds16(Bt + (size_t)(n0 + r0 + srow) * 1024 + k1 + scol,
                  &lB[cur ^ 1][r0 * 64]);
      }
    }
    const u16* la = lA[cur];
    const u16* lb = lB[cur];
#pragma unroll
    for (int ks = 0; ks < 2; ++ks) {
      bf16x8 af[8], bfv[4];
#pragma unroll
      for (int fm = 0; fm < 8; ++fm)
        af[fm] = *(const bf16x8*)(la + (wr * 128 + fm * 16 + fr) * 64 + ks * 32 + kq);
#pragma unroll
      for (int fn = 0; fn < 4; ++fn)
        bfv[fn] = *(const bf16x8*)(lb + (wc * 64 + fn * 16 + fr) * 64 + ks * 32 + kq);
#pragma unroll
      for (int fm = 0; fm < 8; ++fm)
#pragma unroll
        for (int fn = 0; fn < 4; ++fn)
          acc[fm][fn] = __builtin_amdgcn_mfma_f32_16x16x32_bf16(
              af[fm], bfv[fn], acc[fm][fn], 0, 0, 0);
    }
    __syncthreads();  // drains vmcnt (kt+1 landed) + fences buffer switch
    cur ^= 1;
  }

  // epilogue: C/D map row=(lane>>4)*4+rr, col=lane&15 (m89-verified)
  int mat = n0 >> 10;  // block entirely within one of Q/K/V (256 | 1024)
  const float* bp = (mat == 0) ? bias0 : (mat == 1) ? bias1 : bias2;
  int rb0 = m0 + wr * 128 + (lane >> 4) * 4;
  int jb = (n0 & 1023) + wc * 64;
#pragma unroll
  for (int fn = 0; fn < 4; ++fn) {
    int jj = jb + fn * 16 + fr;
    float bv = bp[jj];
    if (mat == 0) bv *= SCALE_L2E;
    if (mat == 2) {
      // V fragment-direct image (same formula as R17 gemm epilogue)
      int h = jj >> 6, hd = jj & 63;
#pragma unroll
      for (int fm = 0; fm < 8; ++fm) {
        int row0 = rb0 + fm * 16;  // multiple of 4, no b/s crossing
        int b = row0 >> 11, s = row0 & 2047;
        int ci = s >> 6, sl = s & 63;
        int slice = sl >> 4, srem = sl & 15;   // srem in {0,4,8,12}
        size_t off = (size_t)(b * 16 + h) * 131072 + ci * 4096 + slice * 1024
                   + ((srem >> 2) & 1) * 512 + hd * 8 + (srem >> 3) * 4;
        ushort4 pk;
        pk.x = f2bf_fast(acc[fm][fn][0] + bv);
        pk.y = f2bf_fast(acc[fm][fn][1] + bv);
        pk.z = f2bf_fast(acc[fm][fn][2] + bv);
        pk.w = f2bf_fast(acc[fm][fn][3] + bv);
        *(ushort4*)(outV + off) = pk;
      }
    } else {
      u16* base = (mat == 0) ? outQ : outK;
#pragma unroll
      for (int fm = 0; fm < 8; ++fm)
#pragma unroll
        for (int rr = 0; rr < 4; ++rr)
          base[(size_t)(rb0 + fm * 16 + rr) * 1024 + jj] =
              f2bf_fast(acc[fm][fn][rr] + bv);
    }
  }
}

// ---------------------------------------------------------------------------
// GEMM (old m97-style 128^2; used for MODE 1 only): C = A x Bt^T + bias.
// 4 waves 2x2, 4x4 of 16x16x32 MFMA; XCD-swizzled.
// ---------------------------------------------------------------------------
template <int MODE>
__global__ __launch_bounds__(256, 3) void gemm_bt(
    const u16* __restrict__ A, const u16* __restrict__ Bt,
    const float* __restrict__ bias0, const float* __restrict__ bias1,
    const float* __restrict__ bias2,
    void* __restrict__ out0v, void* __restrict__ out1v, void* __restrict__ out2v) {
  __shared__ u16 lA[128 * 32];  // [m][k] rows of 32 bf16 (64B)
  __shared__ u16 lB[128 * 32];  // [n][k]
  const int K = 1024;
  int tid = threadIdx.x;
  int wave = tid >> 6, lane = tid & 63;

  int bid = blockIdx.x;
  int n0 = (bid & 7) * 128;                 // XCD owns 1 n-tile (256KB B)
  int m0 = (bid >> 3) * 128;
  int wm = (wave & 1) * 64, wn = (wave >> 1) * 64;

  f32x4 acc[4][4];
#pragma unroll
  for (int i = 0; i < 4; ++i)
#pragma unroll
    for (int jj = 0; jj < 4; ++jj) acc[i][jj] = f32x4{0.f, 0.f, 0.f, 0.f};

  int srow = lane >> 2;          // source row within 16-row stage
  int scol = (lane & 3) * 8;     // source col chunk within 32

  for (int k0 = 0; k0 < K; k0 += 32) {
#pragma unroll
    for (int c = 0; c < 2; ++c) {
      int rbase = wave * 32 + c * 16;
      gld_lds16(A + (size_t)(m0 + rbase + srow) * K + k0 + scol, lA + rbase * 32);
      gld_lds16(Bt + (size_t)(n0 + rbase + srow) * K + k0 + scol, lB + rbase * 32);
    }
    __syncthreads();
    bf16x8 af[4], bfr[4];
#pragma unroll
    for (int mt = 0; mt < 4; ++mt)
      af[mt] = *(const bf16x8*)(lA + (wm + mt * 16 + (lane & 15)) * 32 + (lane >> 4) * 8);
#pragma unroll
    for (int nt = 0; nt < 4; ++nt)
      bfr[nt] = *(const bf16x8*)(lB + (wn + nt * 16 + (lane & 15)) * 32 + (lane >> 4) * 8);
#pragma unroll
    for (int mt = 0; mt < 4; ++mt)
#pragma unroll
      for (int nt = 0; nt < 4; ++nt)
        acc[mt][nt] = __builtin_amdgcn_mfma_f32_16x16x32_bf16(af[mt], bfr[nt], acc[mt][nt], 0, 0, 0);
    __syncthreads();
  }

  // epilogue: C/D layout row=(lane>>4)*4+r, col=lane&15 (m89-verified)
  int rbase0 = m0 + wm + (lane >> 4) * 4;
  int cbase = n0 + wn + (lane & 15);
#pragma unroll
  for (int nt = 0; nt < 4; ++nt) {
    int col = cbase + nt * 16;
    float bv = bias0[col];
    float* o = (float*)out0v;
#pragma unroll
    for (int mt = 0; mt < 4; ++mt)
#pragma unroll
      for (int r = 0; r < 4; ++r) {
        int row = rbase0 + mt * 16 + r;
        o[(size_t)row * 1024 + col] = acc[mt][nt][r] + bv;
      }
  }
}

// ---------------------------------------------------------------------------
// Flash attention (R17, FROZEN): 32x32x16 MFMA + T14 async reg-staging +
// 64 q/wave + fragment-direct V image (b128 PV reads).
// Grid 256 (1 block/CU): block = (bh, 512 q-rows), 8 waves x 64 q.
// ---------------------------------------------------------------------------
__global__ __launch_bounds__(512, 2) void flash_attn(
    const u16* __restrict__ Q, const u16* __restrict__ Kb,
    const u16* __restrict__ Vg, u16* __restrict__ ctx) {
  __shared__ u16 lK[2][64 * 32];  // [k-half][kv-row][32] xor-swizzled (8KB)
  __shared__ u16 lV[4096];        // fragment-direct image [slice][hi][d][8] (8KB)
  int tid = threadIdx.x, wave = tid >> 6, lane = tid & 63;  // wave 0..7

  int F = blockIdx.x;             // 256 flat blocks
  int xcd = F & 7, idx = F >> 3;  // 32 per XCD
  int bh = xcd * 8 + (idx >> 2);  // 8 bh per XCD; q-blocks of a bh adjacent
  int q0 = (idx & 3) * 512;
  int b = bh >> 4, h = bh & 15;
  const u16* Qp = Q + (size_t)b * 2048 * 1024 + h * 64;   // row-major head slice
  const u16* Kp = Kb + (size_t)b * 2048 * 1024 + h * 64;
  const u16* Vp = Vg + (size_t)bh * 131072;

  int ql = lane & 31;   // q (and K-row / V-d row) within 32-block
  int hi = lane >> 5;   // lane half

  // Q B-fragments (persistent): qf[qt][kk] = Q[q0+wave*64+qt*32+ql][kk*16+hi*8+j]
  bf16x8 qf[2][4];
#pragma unroll
  for (int qt = 0; qt < 2; ++qt) {
    const u16* qrow = Qp + (size_t)(q0 + wave * 64 + qt * 32 + ql) * 1024;
#pragma unroll
    for (int kk = 0; kk < 4; ++kk)
      qf[qt][kk] = *(const bf16x8*)(qrow + kk * 16 + hi * 8);
  }

  float lsum[2] = {0.f, 0.f};
  f32x16 o[2][2];  // [qt][dh]: O^T row d=32*dh+(r&3)+8*(r>>2)+4*hi, col q=ql
#pragma unroll
  for (int qt = 0; qt < 2; ++qt)
#pragma unroll
    for (int dh = 0; dh < 2; ++dh) o[qt][dh] = zero16();

  // Staging (T14 reg-staged; split over 8 waves):
  int srow = lane >> 2;
  int schunk = (((lane & 3) ^ ((lane >> 3) & 3)) * 8);
  int kk_w = wave & 1;
  int rb = wave >> 1;      // 0..3
  int stg_row = rb * 16 + srow;
  int rkey = ((lane & 15) >> 1) & 3;  // read-side swizzle key (row%16 == lane&15)

  const u16* gK = Kp + (size_t)stg_row * 1024 + kk_w * 32 + schunk;  // +s0*1024
  const u16* gV = Vp + wave * 512 + lane * 8;                        // +s0*64
  u16* wK = lK[kk_w] + rb * 512 + lane * 8;  // lane's 16B at base+lane*16 (u16*8)
  u16* wV = lV + wave * 512 + lane * 8;

  // prologue: tile 0 regs -> LDS
  i32x4 ldK = *(const i32x4*)gK;
  i32x4 ldV = *(const i32x4*)gV;
  *(i32x4*)wK = ldK;
  *(i32x4*)wV = ldV;
  __syncthreads();

  for (int s0 = 0; s0 < 2048; s0 += 64) {
    bool more = (s0 + 64 < 2048);  // wave-uniform
    if (more) {
      // issue t+1 loads now; latency hides under compute(t)
      ldK = *(const i32x4*)(gK + (size_t)(s0 + 64) * 1024);
      ldV = *(const i32x4*)(gV + (size_t)(s0 + 64) * 64);
    }

#pragma unroll
    for (int sb = 0; sb < 2; ++sb) {
      // K A-fragments (read once, feed both q-tiles):
      bf16x8 kf[4];
      int krb = (sb * 32 + ql) * 32;  // row base (u16)
#pragma unroll
      for (int kk = 0; kk < 4; ++kk)
        kf[kk] = *(const bf16x8*)(lK[kk >> 1] + krb + ((((kk & 1) << 1) | hi) ^ rkey) * 8);

      f32x16 sa0 = zero16(), sa1 = zero16();
#pragma unroll
      for (int kk = 0; kk < 4; ++kk) {
        sa0 = __builtin_amdgcn_mfma_f32_32x32x16_bf16(kf[kk], qf[0][kk], sa0, 0, 0, 0);
        sa1 = __builtin_amdgcn_mfma_f32_32x32x16_bf16(kf[kk], qf[1][kk], sa1, 0, 0, 0);
      }

      // softmax (fixed max 0, log2 units): reg r -> s_local = (r&3)+8*(r>>2)+4*hi
      bf16x8 pu[2][2];
#pragma unroll
      for (int qt = 0; qt < 2; ++qt) {
        float p[16];
#pragma unroll
        for (int r = 0; r < 16; ++r)
          p[r] = exp2_fast(qt == 0 ? sa0[r] : sa1[r]);
        float a0 = (p[0] + p[1]) + (p[2] + p[3]);
        float a1 = (p[4] + p[5]) + (p[6] + p[7]);
        float a2 = (p[8] + p[9]) + (p[10] + p[11]);
        float a3 = (p[12] + p[13]) + (p[14] + p[15]);
        lsum[qt] += (a0 + a1) + (a2 + a3);
#pragma unroll
        for (int ss = 0; ss < 2; ++ss) {
          union { u32 w[4]; bf16x8 v; } pk_;
          pk_.w[0] = pk2(p[8 * ss + 0], p[8 * ss + 1]);
          pk_.w[1] = pk2(p[8 * ss + 2], p[8 * ss + 3]);
          pk_.w[2] = pk2(p[8 * ss + 4], p[8 * ss + 5]);
          pk_.w[3] = pk2(p[8 * ss + 6], p[8 * ss + 7]);
          pu[qt][ss] = pk_.v;
        }
      }

      // PV: per 16-s slice ss, per d-half dh: ONE b128 A-frag read from the
      // fragment-direct image (pi-order k-slots match register-native P).
#pragma unroll
      for (int ss = 0; ss < 2; ++ss) {
        int vbase = (sb * 2 + ss) * 1024 + hi * 512 + ql * 8;
#pragma unroll
        for (int dh = 0; dh < 2; ++dh) {
          bf16x8 vf = *(const bf16x8*)(lV + vbase + dh * 256);
          o[0][dh] = __builtin_amdgcn_mfma_f32_32x32x16_bf16(vf, pu[0][ss], o[0][dh], 0, 0, 0);
          o[1][dh] = __builtin_amdgcn_mfma_f32_32x32x16_bf16(vf, pu[1][ss], o[1][dh], 0, 0, 0);
        }
      }
    }

    __syncthreads();   // all waves done reading tile t; t+1 loads retired
    if (more) {
      *(i32x4*)wK = ldK;
      *(i32x4*)wV = ldV;
    }
    __syncthreads();   // t+1 LDS writes visible
  }

  // epilogue: lsum pairs live on lanes l and l^32 (same q) -> one shfl_xor;
  // normalize, write ctx[b][q][h][d], d = 32*dh + 8*(r>>2) + 4*hi + (r&3)
#pragma unroll
  for (int qt = 0; qt < 2; ++qt) {
    float rs = lsum[qt] + __shfl_xor(lsum[qt], 32);
    float inv = 1.0f / fmaxf(rs, 1e-30f);
    int q = q0 + wave * 64 + qt * 32 + ql;
    size_t rowbase = ((size_t)(b * 2048 + q) * 16 + h) * 64;
#pragma unroll
    for (int dh = 0; dh < 2; ++dh)
#pragma unroll
      for (int rr = 0; rr < 4; ++rr) {
        ushort4 pk;
        pk.x = f2bf_fast(o[qt][dh][4 * rr + 0] * inv);
        pk.y = f2bf_fast(o[qt][dh][4 * rr + 1] * inv);
        pk.z = f2bf_fast(o[qt][dh][4 * rr + 2] * inv);
        pk.w = f2bf_fast(o[qt][dh][4 * rr + 3] * inv);
        *(ushort4*)(ctx + rowbase + dh * 32 + rr * 8 + hi * 4) = pk;
      }
  }
}

// ---------------------------------------------------------------------------
extern "C" void kernel_launch(void* const* d_in, const int* in_sizes, int n_in,
                              void* d_out, int out_size, void* d_ws, size_t ws_size,
                              hipStream_t stream) {
  const float* x  = (const float*)d_in[0];
  const float* wq = (const float*)d_in[1];
  const float* bq = (const float*)d_in[2];
  const float* wk = (const float*)d_in[3];
  const float* bk = (const float*)d_in[4];
  const float* wv = (const float*)d_in[5];
  const float* bv = (const float*)d_in[6];
  const float* wo = (const float*)d_in[7];
  const float* bo = (const float*)d_in[8];

  u16* ws = (u16*)d_ws;
  u16* xb     = ws;                            // 8192*1024 bf16 (16MB)
  u16* wt_qkv = xb + (size_t)8192 * 1024;      // 3072*1024 (6MB)
  u16* wt_o   = wt_qkv + (size_t)3072 * 1024;  // 1024*1024 (2MB)
  u16* Qb     = wt_o + (size_t)1024 * 1024;    // row-major [B,S,D] (16MB)
  u16* Kbuf   = Qb + (size_t)8192 * 1024;      // row-major [B,S,D] (16MB)
  u16* Vgb    = Kbuf + (size_t)8192 * 1024;    // fragment-direct image (16MB)
  u16* ctx    = Vgb + (size_t)8192 * 1024;     // [B,S,D] bf16 (16MB)
  // total ws use: 88MB

  convert_x<<<8192, 256, 0, stream>>>(x, xb);
  pack_weights<<<dim3(16, 16, 4), 256, 0, stream>>>(wq, wk, wv, wo, wt_qkv, wt_o);
  gemm256_qkv<<<384, 512, 0, stream>>>(xb, wt_qkv, bq, bk, bv, Qb, Kbuf, Vgb);
  flash_attn<<<256, 512, 0, stream>>>(Qb, Kbuf, Vgb, ctx);
  gemm_bt<1><<<512, 256, 0, stream>>>(ctx, wt_o, bo, nullptr, nullptr,
                                      d_out, nullptr, nullptr);
}

// Round 13
// 279.716 us; speedup vs baseline: 1.0953x; 1.0953x over previous
//
#include <hip/hip_runtime.h>
#include <stdint.h>

// Problem: B=4, S=2048, D=1024, H=16, HD=64. I/O fp32; internal compute bf16
// MFMA with fp32 accumulation.
// SCALE*log2(e) folded into wq^T and bq -> flash uses exp2 directly with a
// FIXED softmax max of 0 (shift-invariant; logits statically bounded ~|9|).
// Flash: R17 structure FROZEN (93.4us floor; R13/R14/R16/R17 nulls).
// GEMM lineage: old m97-style gemm<0> ~79us (~650 TF). R19 256^2/BK=64
// 2-phase dbuf = 103us (500 TF) REGRESSED, but produced direct counters:
//   (a) grid 384 = 1.5 blocks/CU -> 75% efficiency (500*4/3 ~= 667 = catalog
//       2ph range => imbalance explains the whole gap),
//   (b) SQ_LDS_BANK_CONFLICT 14.16M (~22% wall): [*][64] tile rows stride
//       128B -> 16-way conflict on ds_read_b128 (T2 regime).
// R20 (2nd submit; R12 bench was an infra failure -- same flaky error that
// hit known-good R0/R17; swizzle write/read keys, bank math, LDS/global
// bounds re-audited, no fault path): keep issue-early 2-phase dbuf; fix both
// measured defects:
//   geometry 128x256/BK=32 -> grid 768 = EXACTLY 3 blocks/CU (balanced);
//   LDS 48KB dbuf; launch_bounds(512,4);
//   XOR source-preswizzle on staging + swizzled reads -> 2-way (free, m136).
//   Write key ((row%16)>>1)&3 == read key (fr>>1)&3.
// Flash, gemm_bt<1>, convert, pack frozen.

typedef __attribute__((ext_vector_type(8))) short bf16x8;
typedef __attribute__((ext_vector_type(4))) short bf16x4;
typedef __attribute__((ext_vector_type(4))) float f32x4;
typedef __attribute__((ext_vector_type(16))) float f32x16;
typedef __attribute__((ext_vector_type(4))) int i32x4;
typedef unsigned short u16;
typedef unsigned int u32;

#define AS1 __attribute__((address_space(1)))
#define AS3 __attribute__((address_space(3)))

#define SCALE_L2E 0.18033688011112042f  // 0.125 * log2(e)

__device__ __forceinline__ void gld_lds16(const void* g, void* l) {
  // async global->LDS DMA: lane i's 16B land at (wave-uniform) l + i*16;
  // global source address is per-lane (enables source-preswizzle).
  __builtin_amdgcn_global_load_lds((const AS1 void*)g, (AS3 void*)l, 16, 0, 0);
}

__device__ __forceinline__ u16 f2bf(float f) {
  u32 x = __builtin_bit_cast(u32, f);
  x += 0x7fff + ((x >> 16) & 1);  // RNE
  return (u16)(x >> 16);
}

__device__ __forceinline__ u16 f2bf_fast(float a) {
#if __has_builtin(__builtin_amdgcn_cvt_pk_bf16_f32)
  auto v = __builtin_amdgcn_cvt_pk_bf16_f32(a, a);  // both halves = a: order-immune
  return (u16)(__builtin_bit_cast(u32, v) & 0xffffu);
#else
  return f2bf(a);
#endif
}

__device__ __forceinline__ u32 pk2(float a, float b) {  // lo16=a, hi16=b
#if __has_builtin(__builtin_amdgcn_cvt_pk_bf16_f32)
  return __builtin_bit_cast(u32, __builtin_amdgcn_cvt_pk_bf16_f32(a, b));
#else
  return (u32)f2bf(a) | ((u32)f2bf(b) << 16);
#endif
}

__device__ __forceinline__ float exp2_fast(float x) {
#if __has_builtin(__builtin_amdgcn_exp2f)
  return __builtin_amdgcn_exp2f(x);
#else
  return exp2f(x);
#endif
}

__device__ __forceinline__ f32x16 zero16() {
  f32x16 z;
#pragma unroll
  for (int i = 0; i < 16; ++i) z[i] = 0.f;
  return z;
}

// ---------------------------------------------------------------------------
// fp32 -> bf16 conversion of x (8M elements)
// ---------------------------------------------------------------------------
__global__ __launch_bounds__(256) void convert_x(const float* __restrict__ x,
                                                 u16* __restrict__ xb) {
  int i = (blockIdx.x * 256 + threadIdx.x) * 4;
  float4 v = *(const float4*)(x + i);
  ushort4 o;
  o.x = f2bf(v.x); o.y = f2bf(v.y); o.z = f2bf(v.z); o.w = f2bf(v.w);
  *(ushort4*)(xb + i) = o;
}

// ---------------------------------------------------------------------------
// Weight pack (fp32 [K][N] -> bf16 [N][K]); wq scaled by SCALE*log2(e)
// ---------------------------------------------------------------------------
__global__ __launch_bounds__(256) void pack_weights(
    const float* __restrict__ wq, const float* __restrict__ wk,
    const float* __restrict__ wv, const float* __restrict__ wo,
    u16* __restrict__ wt_qkv, u16* __restrict__ wt_o) {
  __shared__ float tile[64][65];
  int mat = blockIdx.z;
  const float* src = (mat == 0) ? wq : (mat == 1) ? wk : (mat == 2) ? wv : wo;
  int k0 = blockIdx.y * 64, j0 = blockIdx.x * 64;
  int t = threadIdx.x;
  int lr = t >> 6;   // 0..3
  int lc = t & 63;
#pragma unroll
  for (int it = 0; it < 16; ++it) {
    int r = it * 4 + lr;
    tile[r][lc] = src[(size_t)(k0 + r) * 1024 + j0 + lc];
  }
  __syncthreads();
  u16* dst = (mat == 3) ? wt_o : (wt_qkv + (size_t)mat * 1024 * 1024);
#pragma unroll
  for (int it = 0; it < 16; ++it) {
    int nl = it * 4 + lr;
    float v = tile[lc][nl];
    if (mat == 0) v *= SCALE_L2E;  // fold attention scale + log2(e)
    dst[(size_t)(j0 + nl) * 1024 + k0 + lc] = f2bf(v);
  }
}

// ---------------------------------------------------------------------------
// gemm_qkv (R20): fused QKV GEMM, 128x256 tile, BK=32, 2-phase issue-early
// dbuf, XOR-swizzled LDS. Grid 768 (= 3 blocks/CU exactly, balanced).
// 512 thr = 8 waves (2M x 4N); per-wave 64x64 out = acc[4][4].
// LDS: 2 bufs x (A 8KB + B 16KB) = 48KB.
// Swizzle: LDS[row][pos] holds global chunk pos^key(row), key(row)=(row>>1)&3
//   (16B chunks, 4 per 64B row). Stage: lane i covers row r0+(i>>2), pos i&3,
//   source chunk (i&3)^((i>>3)&3). Read: pos = (lane>>4) ^ ((fr>>1)&3).
//   16-way -> 2-way (free).
// Per K-tile: issue 3 DMAs (1 A + 2 B per wave) for kt+1 -> buf^1; compute
// buf (4+4 ds_read_b128, 16 MFMA); one __syncthreads (drain+fence).
// XCD map: xcd=bid&7 owns m-tiles xcd*8..+8 x all 12 n-tiles (bijective);
// consecutive j share the 512KB B-panel (L2 reuse).
// Epilogue: mat uniform per block (BN=256 | 1024). Q,K row-major bf16;
// V fragment-direct image (same formula as R17/R19).
// ---------------------------------------------------------------------------
__global__ __launch_bounds__(512, 4) void gemm_qkv(
    const u16* __restrict__ A, const u16* __restrict__ Bt,
    const float* __restrict__ bias0, const float* __restrict__ bias1,
    const float* __restrict__ bias2,
    u16* __restrict__ outQ, u16* __restrict__ outK, u16* __restrict__ outV) {
  __shared__ u16 lA[2][128 * 32];  // [buf][m][k(32)] 8KB each
  __shared__ u16 lB[2][256 * 32];  // [buf][n][k(32)] 16KB each
  int tid = threadIdx.x;
  int wave = tid >> 6, lane = tid & 63;
  int wr = wave >> 2, wc = wave & 3;  // 2M x 4N wave grid

  int bid = blockIdx.x;
  int xcd = bid & 7, j = bid >> 3;          // j 0..95
  int m0 = (xcd * 8 + (j & 7)) * 128;       // m-tiles 0..63 (bijective)
  int n0 = (j >> 3) * 256;                  // n-tiles 0..11

  f32x4 acc[4][4];
#pragma unroll
  for (int fm = 0; fm < 4; ++fm)
#pragma unroll
    for (int fn = 0; fn < 4; ++fn) acc[fm][fn] = f32x4{0.f, 0.f, 0.f, 0.f};

  int srow = lane >> 2;                               // 0..15 within a DMA
  int schunk = ((lane & 3) ^ ((lane >> 3) & 3)) * 8;  // source chunk (elems)
  int fr = lane & 15;
  int rpos = (((lane >> 4) ^ ((fr >> 1) & 3))) * 8;   // read pos (elems)

  const u16* Asrc = A + (size_t)(m0 + wave * 16 + srow) * 1024 + schunk;
  const u16* Bsrc0 = Bt + (size_t)(n0 + wave * 32 + srow) * 1024 + schunk;
  const u16* Bsrc1 = Bsrc0 + (size_t)16 * 1024;

  // prologue: stage K-tile 0 into buf 0
  gld_lds16(Asrc, &lA[0][wave * 16 * 32]);
  gld_lds16(Bsrc0, &lB[0][wave * 32 * 32]);
  gld_lds16(Bsrc1, &lB[0][(wave * 32 + 16) * 32]);
  __syncthreads();

  int cur = 0;
  for (int kt = 0; kt < 32; ++kt) {
    if (kt < 31) {  // issue next-tile stages; they land under compute
      int k1 = (kt + 1) * 32;
      gld_lds16(Asrc + k1, &lA[cur ^ 1][wave * 16 * 32]);
      gld_lds16(Bsrc0 + k1, &lB[cur ^ 1][wave * 32 * 32]);
      gld_lds16(Bsrc1 + k1, &lB[cur ^ 1][(wave * 32 + 16) * 32]);
    }
    bf16x8 af[4], bfv[4];
#pragma unroll
    for (int fm = 0; fm < 4; ++fm)
      af[fm] = *(const bf16x8*)(&lA[cur][(wr * 64 + fm * 16 + fr) * 32 + rpos]);
#pragma unroll
    for (int fn = 0; fn < 4; ++fn)
      bfv[fn] = *(const bf16x8*)(&lB[cur][(wc * 64 + fn * 16 + fr) * 32 + rpos]);
#pragma unroll
    for (int fm = 0; fm < 4; ++fm)
#pragma unroll
      for (int fn = 0; fn < 4; ++fn)
        acc[fm][fn] = __builtin_amdgcn_mfma_f32_16x16x32_bf16(
            af[fm], bfv[fn], acc[fm][fn], 0, 0, 0);
    __syncthreads();  // drains vmcnt (kt+1 landed) + fences buffer switch
    cur ^= 1;
  }

  // epilogue: C/D map row=(lane>>4)*4+rr, col=lane&15 (m89-verified)
  int mat = n0 >> 10;  // block entirely within one of Q/K/V (256 | 1024)
  const float* bp = (mat == 0) ? bias0 : (mat == 1) ? bias1 : bias2;
  int rb0 = m0 + wr * 64 + (lane >> 4) * 4;
  int jb = (n0 & 1023) + wc * 64;
#pragma unroll
  for (int fn = 0; fn < 4; ++fn) {
    int jj = jb + fn * 16 + fr;
    float bv = bp[jj];
    if (mat == 0) bv *= SCALE_L2E;
    if (mat == 2) {
      // V fragment-direct image (same formula as R17 epilogue)
      int h = jj >> 6, hd = jj & 63;
#pragma unroll
      for (int fm = 0; fm < 4; ++fm) {
        int row0 = rb0 + fm * 16;  // multiple of 4, no b/s crossing
        int b = row0 >> 11, s = row0 & 2047;
        int ci = s >> 6, sl = s & 63;
        int slice = sl >> 4, srem = sl & 15;   // srem in {0,4,8,12}
        size_t off = (size_t)(b * 16 + h) * 131072 + ci * 4096 + slice * 1024
                   + ((srem >> 2) & 1) * 512 + hd * 8 + (srem >> 3) * 4;
        ushort4 pk;
        pk.x = f2bf_fast(acc[fm][fn][0] + bv);
        pk.y = f2bf_fast(acc[fm][fn][1] + bv);
        pk.z = f2bf_fast(acc[fm][fn][2] + bv);
        pk.w = f2bf_fast(acc[fm][fn][3] + bv);
        *(ushort4*)(outV + off) = pk;
      }
    } else {
      u16* base = (mat == 0) ? outQ : outK;
#pragma unroll
      for (int fm = 0; fm < 4; ++fm)
#pragma unroll
        for (int rr = 0; rr < 4; ++rr)
          base[(size_t)(rb0 + fm * 16 + rr) * 1024 + jj] =
              f2bf_fast(acc[fm][fn][rr] + bv);
    }
  }
}

// ---------------------------------------------------------------------------
// GEMM (old m97-style 128^2; used for MODE 1 only): C = A x Bt^T + bias.
// 4 waves 2x2, 4x4 of 16x16x32 MFMA; XCD-swizzled. 512 blocks, balanced.
// ---------------------------------------------------------------------------
template <int MODE>
__global__ __launch_bounds__(256, 3) void gemm_bt(
    const u16* __restrict__ A, const u16* __restrict__ Bt,
    const float* __restrict__ bias0, const float* __restrict__ bias1,
    const float* __restrict__ bias2,
    void* __restrict__ out0v, void* __restrict__ out1v, void* __restrict__ out2v) {
  __shared__ u16 lA[128 * 32];  // [m][k] rows of 32 bf16 (64B)
  __shared__ u16 lB[128 * 32];  // [n][k]
  const int K = 1024;
  int tid = threadIdx.x;
  int wave = tid >> 6, lane = tid & 63;

  int bid = blockIdx.x;
  int n0 = (bid & 7) * 128;                 // XCD owns 1 n-tile (256KB B)
  int m0 = (bid >> 3) * 128;
  int wm = (wave & 1) * 64, wn = (wave >> 1) * 64;

  f32x4 acc[4][4];
#pragma unroll
  for (int i = 0; i < 4; ++i)
#pragma unroll
    for (int jj = 0; jj < 4; ++jj) acc[i][jj] = f32x4{0.f, 0.f, 0.f, 0.f};

  int srow = lane >> 2;          // source row within 16-row stage
  int scol = (lane & 3) * 8;     // source col chunk within 32

  for (int k0 = 0; k0 < K; k0 += 32) {
#pragma unroll
    for (int c = 0; c < 2; ++c) {
      int rbase = wave * 32 + c * 16;
      gld_lds16(A + (size_t)(m0 + rbase + srow) * K + k0 + scol, lA + rbase * 32);
      gld_lds16(Bt + (size_t)(n0 + rbase + srow) * K + k0 + scol, lB + rbase * 32);
    }
    __syncthreads();
    bf16x8 af[4], bfr[4];
#pragma unroll
    for (int mt = 0; mt < 4; ++mt)
      af[mt] = *(const bf16x8*)(lA + (wm + mt * 16 + (lane & 15)) * 32 + (lane >> 4) * 8);
#pragma unroll
    for (int nt = 0; nt < 4; ++nt)
      bfr[nt] = *(const bf16x8*)(lB + (wn + nt * 16 + (lane & 15)) * 32 + (lane >> 4) * 8);
#pragma unroll
    for (int mt = 0; mt < 4; ++mt)
#pragma unroll
      for (int nt = 0; nt < 4; ++nt)
        acc[mt][nt] = __builtin_amdgcn_mfma_f32_16x16x32_bf16(af[mt], bfr[nt], acc[mt][nt], 0, 0, 0);
    __syncthreads();
  }

  // epilogue: C/D layout row=(lane>>4)*4+r, col=lane&15 (m89-verified)
  int rbase0 = m0 + wm + (lane >> 4) * 4;
  int cbase = n0 + wn + (lane & 15);
#pragma unroll
  for (int nt = 0; nt < 4; ++nt) {
    int col = cbase + nt * 16;
    float bv = bias0[col];
    float* o = (float*)out0v;
#pragma unroll
    for (int mt = 0; mt < 4; ++mt)
#pragma unroll
      for (int r = 0; r < 4; ++r) {
        int row = rbase0 + mt * 16 + r;
        o[(size_t)row * 1024 + col] = acc[mt][nt][r] + bv;
      }
  }
}

// ---------------------------------------------------------------------------
// Flash attention (R17, FROZEN): 32x32x16 MFMA + T14 async reg-staging +
// 64 q/wave + fragment-direct V image (b128 PV reads).
// Grid 256 (1 block/CU): block = (bh, 512 q-rows), 8 waves x 64 q.
// ---------------------------------------------------------------------------
__global__ __launch_bounds__(512, 2) void flash_attn(
    const u16* __restrict__ Q, const u16* __restrict__ Kb,
    const u16* __restrict__ Vg, u16* __restrict__ ctx) {
  __shared__ u16 lK[2][64 * 32];  // [k-half][kv-row][32] xor-swizzled (8KB)
  __shared__ u16 lV[4096];        // fragment-direct image [slice][hi][d][8] (8KB)
  int tid = threadIdx.x, wave = tid >> 6, lane = tid & 63;  // wave 0..7

  int F = blockIdx.x;             // 256 flat blocks
  int xcd = F & 7, idx = F >> 3;  // 32 per XCD
  int bh = xcd * 8 + (idx >> 2);  // 8 bh per XCD; q-blocks of a bh adjacent
  int q0 = (idx & 3) * 512;
  int b = bh >> 4, h = bh & 15;
  const u16* Qp = Q + (size_t)b * 2048 * 1024 + h * 64;   // row-major head slice
  const u16* Kp = Kb + (size_t)b * 2048 * 1024 + h * 64;
  const u16* Vp = Vg + (size_t)bh * 131072;

  int ql = lane & 31;   // q (and K-row / V-d row) within 32-block
  int hi = lane >> 5;   // lane half

  // Q B-fragments (persistent): qf[qt][kk] = Q[q0+wave*64+qt*32+ql][kk*16+hi*8+j]
  bf16x8 qf[2][4];
#pragma unroll
  for (int qt = 0; qt < 2; ++qt) {
    const u16* qrow = Qp + (size_t)(q0 + wave * 64 + qt * 32 + ql) * 1024;
#pragma unroll
    for (int kk = 0; kk < 4; ++kk)
      qf[qt][kk] = *(const bf16x8*)(qrow + kk * 16 + hi * 8);
  }

  float lsum[2] = {0.f, 0.f};
  f32x16 o[2][2];  // [qt][dh]: O^T row d=32*dh+(r&3)+8*(r>>2)+4*hi, col q=ql
#pragma unroll
  for (int qt = 0; qt < 2; ++qt)
#pragma unroll
    for (int dh = 0; dh < 2; ++dh) o[qt][dh] = zero16();

  // Staging (T14 reg-staged; split over 8 waves):
  int srow = lane >> 2;
  int schunk = (((lane & 3) ^ ((lane >> 3) & 3)) * 8);
  int kk_w = wave & 1;
  int rb = wave >> 1;      // 0..3
  int stg_row = rb * 16 + srow;
  int rkey = ((lane & 15) >> 1) & 3;  // read-side swizzle key (row%16 == lane&15)

  const u16* gK = Kp + (size_t)stg_row * 1024 + kk_w * 32 + schunk;  // +s0*1024
  const u16* gV = Vp + wave * 512 + lane * 8;                        // +s0*64
  u16* wK = lK[kk_w] + rb * 512 + lane * 8;  // lane's 16B at base+lane*16 (u16*8)
  u16* wV = lV + wave * 512 + lane * 8;

  // prologue: tile 0 regs -> LDS
  i32x4 ldK = *(const i32x4*)gK;
  i32x4 ldV = *(const i32x4*)gV;
  *(i32x4*)wK = ldK;
  *(i32x4*)wV = ldV;
  __syncthreads();

  for (int s0 = 0; s0 < 2048; s0 += 64) {
    bool more = (s0 + 64 < 2048);  // wave-uniform
    if (more) {
      // issue t+1 loads now; latency hides under compute(t)
      ldK = *(const i32x4*)(gK + (size_t)(s0 + 64) * 1024);
      ldV = *(const i32x4*)(gV + (size_t)(s0 + 64) * 64);
    }

#pragma unroll
    for (int sb = 0; sb < 2; ++sb) {
      // K A-fragments (read once, feed both q-tiles):
      bf16x8 kf[4];
      int krb = (sb * 32 + ql) * 32;  // row base (u16)
#pragma unroll
      for (int kk = 0; kk < 4; ++kk)
        kf[kk] = *(const bf16x8*)(lK[kk >> 1] + krb + ((((kk & 1) << 1) | hi) ^ rkey) * 8);

      f32x16 sa0 = zero16(), sa1 = zero16();
#pragma unroll
      for (int kk = 0; kk < 4; ++kk) {
        sa0 = __builtin_amdgcn_mfma_f32_32x32x16_bf16(kf[kk], qf[0][kk], sa0, 0, 0, 0);
        sa1 = __builtin_amdgcn_mfma_f32_32x32x16_bf16(kf[kk], qf[1][kk], sa1, 0, 0, 0);
      }

      // softmax (fixed max 0, log2 units): reg r -> s_local = (r&3)+8*(r>>2)+4*hi
      bf16x8 pu[2][2];
#pragma unroll
      for (int qt = 0; qt < 2; ++qt) {
        float p[16];
#pragma unroll
        for (int r = 0; r < 16; ++r)
          p[r] = exp2_fast(qt == 0 ? sa0[r] : sa1[r]);
        float a0 = (p[0] + p[1]) + (p[2] + p[3]);
        float a1 = (p[4] + p[5]) + (p[6] + p[7]);
        float a2 = (p[8] + p[9]) + (p[10] + p[11]);
        float a3 = (p[12] + p[13]) + (p[14] + p[15]);
        lsum[qt] += (a0 + a1) + (a2 + a3);
#pragma unroll
        for (int ss = 0; ss < 2; ++ss) {
          union { u32 w[4]; bf16x8 v; } pk_;
          pk_.w[0] = pk2(p[8 * ss + 0], p[8 * ss + 1]);
          pk_.w[1] = pk2(p[8 * ss + 2], p[8 * ss + 3]);
          pk_.w[2] = pk2(p[8 * ss + 4], p[8 * ss + 5]);
          pk_.w[3] = pk2(p[8 * ss + 6], p[8 * ss + 7]);
          pu[qt][ss] = pk_.v;
        }
      }

      // PV: per 16-s slice ss, per d-half dh: ONE b128 A-frag read from the
      // fragment-direct image (pi-order k-slots match register-native P).
#pragma unroll
      for (int ss = 0; ss < 2; ++ss) {
        int vbase = (sb * 2 + ss) * 1024 + hi * 512 + ql * 8;
#pragma unroll
        for (int dh = 0; dh < 2; ++dh) {
          bf16x8 vf = *(const bf16x8*)(lV + vbase + dh * 256);
          o[0][dh] = __builtin_amdgcn_mfma_f32_32x32x16_bf16(vf, pu[0][ss], o[0][dh], 0, 0, 0);
          o[1][dh] = __builtin_amdgcn_mfma_f32_32x32x16_bf16(vf, pu[1][ss], o[1][dh], 0, 0, 0);
        }
      }
    }

    __syncthreads();   // all waves done reading tile t; t+1 loads retired
    if (more) {
      *(i32x4*)wK = ldK;
      *(i32x4*)wV = ldV;
    }
    __syncthreads();   // t+1 LDS writes visible
  }

  // epilogue: lsum pairs live on lanes l and l^32 (same q) -> one shfl_xor;
  // normalize, write ctx[b][q][h][d], d = 32*dh + 8*(r>>2) + 4*hi + (r&3)
#pragma unroll
  for (int qt = 0; qt < 2; ++qt) {
    float rs = lsum[qt] + __shfl_xor(lsum[qt], 32);
    float inv = 1.0f / fmaxf(rs, 1e-30f);
    int q = q0 + wave * 64 + qt * 32 + ql;
    size_t rowbase = ((size_t)(b * 2048 + q) * 16 + h) * 64;
#pragma unroll
    for (int dh = 0; dh < 2; ++dh)
#pragma unroll
      for (int rr = 0; rr < 4; ++rr) {
        ushort4 pk;
        pk.x = f2bf_fast(o[qt][dh][4 * rr + 0] * inv);
        pk.y = f2bf_fast(o[qt][dh][4 * rr + 1] * inv);
        pk.z = f2bf_fast(o[qt][dh][4 * rr + 2] * inv);
        pk.w = f2bf_fast(o[qt][dh][4 * rr + 3] * inv);
        *(ushort4*)(ctx + rowbase + dh * 32 + rr * 8 + hi * 4) = pk;
      }
  }
}

// ---------------------------------------------------------------------------
extern "C" void kernel_launch(void* const* d_in, const int* in_sizes, int n_in,
                              void* d_out, int out_size, void* d_ws, size_t ws_size,
                              hipStream_t stream) {
  const float* x  = (const float*)d_in[0];
  const float* wq = (const float*)d_in[1];
  const float* bq = (const float*)d_in[2];
  const float* wk = (const float*)d_in[3];
  const float* bk = (const float*)d_in[4];
  const float* wv = (const float*)d_in[5];
  const float* bv = (const float*)d_in[6];
  const float* wo = (const float*)d_in[7];
  const float* bo = (const float*)d_in[8];

  u16* ws = (u16*)d_ws;
  u16* xb     = ws;                            // 8192*1024 bf16 (16MB)
  u16* wt_qkv = xb + (size_t)8192 * 1024;      // 3072*1024 (6MB)
  u16* wt_o   = wt_qkv + (size_t)3072 * 1024;  // 1024*1024 (2MB)
  u16* Qb     = wt_o + (size_t)1024 * 1024;    // row-major [B,S,D] (16MB)
  u16* Kbuf   = Qb + (size_t)8192 * 1024;      // row-major [B,S,D] (16MB)
  u16* Vgb    = Kbuf + (size_t)8192 * 1024;    // fragment-direct image (16MB)
  u16* ctx    = Vgb + (size_t)8192 * 1024;     // [B,S,D] bf16 (16MB)
  // total ws use: 88MB

  convert_x<<<8192, 256, 0, stream>>>(x, xb);
  pack_weights<<<dim3(16, 16, 4), 256, 0, stream>>>(wq, wk, wv, wo, wt_qkv, wt_o);
  gemm_qkv<<<768, 512, 0, stream>>>(xb, wt_qkv, bq, bk, bv, Qb, Kbuf, Vgb);
  flash_attn<<<256, 512, 0, stream>>>(Qb, Kbuf, Vgb, ctx);
  gemm_bt<1><<<512, 256, 0, stream>>>(ctx, wt_o, bo, nullptr, nullptr,
                                      d_out, nullptr, nullptr);
}

// Round 14
// 278.945 us; speedup vs baseline: 1.0984x; 1.0028x over previous
//
#include <hip/hip_runtime.h>
#include <stdint.h>

// Problem: B=4, S=2048, D=1024, H=16, HD=64. I/O fp32; internal compute bf16
// MFMA with fp32 accumulation.
// SCALE*log2(e) folded into wq^T and bq -> flash uses exp2 directly with a
// FIXED softmax max of 0 (shift-invariant; logits statically bounded ~|9|).
// Flash: R17 structure FROZEN (~90us floor; R13/R14/R16/R17 nulls).
// GEMM lineage: R19 256^2 2ph = 103us (grid imbalance + 16-way conflicts);
// R20 128x256/BK=32, balanced grid 768, XOR swizzle = ~78us (~660 TF) WIN --
// exactly the 2-phase structural ceiling (catalog 655-735 TF). The 2-phase
// defect: __syncthreads per K-tile drains vmcnt(0), killing pipeline depth.
// R21 (this round): counted-vmcnt TRIPLE-BUFFER pipeline (T3/T4 + T5) on
// R20's verified geometry. Per iter t:
//   stage(t+2 -> b[(t+2)%3])           (3 DMAs/wave; buffer's readers done
//                                       at barrier t-1 -> no WAR race)
//   ds_read b[t%3] + 16 MFMA           (setprio(1) cluster, T5)
//   s_waitcnt vmcnt(3)                 (own t+1 loads retired; vmcnt retires
//                                       in issue order, m135)
//   s_barrier (raw; no drain)          (-> ALL waves' t+1 landed)
// LDS 3x24KB = 72KB -> 2 blocks/CU. asm "memory" fences pin loads across the
// raw barrier. Epilogue iters drain vmcnt(0). m218: counted-vs-drain is the
// 8-phase lever (+38-73%); conservative expectation here +20-40%.
// Flash, gemm_bt<1>, convert, pack frozen.

typedef __attribute__((ext_vector_type(8))) short bf16x8;
typedef __attribute__((ext_vector_type(4))) short bf16x4;
typedef __attribute__((ext_vector_type(4))) float f32x4;
typedef __attribute__((ext_vector_type(16))) float f32x16;
typedef __attribute__((ext_vector_type(4))) int i32x4;
typedef unsigned short u16;
typedef unsigned int u32;

#define AS1 __attribute__((address_space(1)))
#define AS3 __attribute__((address_space(3)))

#define SCALE_L2E 0.18033688011112042f  // 0.125 * log2(e)

__device__ __forceinline__ void gld_lds16(const void* g, void* l) {
  // async global->LDS DMA: lane i's 16B land at (wave-uniform) l + i*16;
  // global source address is per-lane (enables source-preswizzle).
  __builtin_amdgcn_global_load_lds((const AS1 void*)g, (AS3 void*)l, 16, 0, 0);
}

__device__ __forceinline__ u16 f2bf(float f) {
  u32 x = __builtin_bit_cast(u32, f);
  x += 0x7fff + ((x >> 16) & 1);  // RNE
  return (u16)(x >> 16);
}

__device__ __forceinline__ u16 f2bf_fast(float a) {
#if __has_builtin(__builtin_amdgcn_cvt_pk_bf16_f32)
  auto v = __builtin_amdgcn_cvt_pk_bf16_f32(a, a);  // both halves = a: order-immune
  return (u16)(__builtin_bit_cast(u32, v) & 0xffffu);
#else
  return f2bf(a);
#endif
}

__device__ __forceinline__ u32 pk2(float a, float b) {  // lo16=a, hi16=b
#if __has_builtin(__builtin_amdgcn_cvt_pk_bf16_f32)
  return __builtin_bit_cast(u32, __builtin_amdgcn_cvt_pk_bf16_f32(a, b));
#else
  return (u32)f2bf(a) | ((u32)f2bf(b) << 16);
#endif
}

__device__ __forceinline__ float exp2_fast(float x) {
#if __has_builtin(__builtin_amdgcn_exp2f)
  return __builtin_amdgcn_exp2f(x);
#else
  return exp2f(x);
#endif
}

__device__ __forceinline__ f32x16 zero16() {
  f32x16 z;
#pragma unroll
  for (int i = 0; i < 16; ++i) z[i] = 0.f;
  return z;
}

// ---------------------------------------------------------------------------
// fp32 -> bf16 conversion of x (8M elements)
// ---------------------------------------------------------------------------
__global__ __launch_bounds__(256) void convert_x(const float* __restrict__ x,
                                                 u16* __restrict__ xb) {
  int i = (blockIdx.x * 256 + threadIdx.x) * 4;
  float4 v = *(const float4*)(x + i);
  ushort4 o;
  o.x = f2bf(v.x); o.y = f2bf(v.y); o.z = f2bf(v.z); o.w = f2bf(v.w);
  *(ushort4*)(xb + i) = o;
}

// ---------------------------------------------------------------------------
// Weight pack (fp32 [K][N] -> bf16 [N][K]); wq scaled by SCALE*log2(e)
// ---------------------------------------------------------------------------
__global__ __launch_bounds__(256) void pack_weights(
    const float* __restrict__ wq, const float* __restrict__ wk,
    const float* __restrict__ wv, const float* __restrict__ wo,
    u16* __restrict__ wt_qkv, u16* __restrict__ wt_o) {
  __shared__ float tile[64][65];
  int mat = blockIdx.z;
  const float* src = (mat == 0) ? wq : (mat == 1) ? wk : (mat == 2) ? wv : wo;
  int k0 = blockIdx.y * 64, j0 = blockIdx.x * 64;
  int t = threadIdx.x;
  int lr = t >> 6;   // 0..3
  int lc = t & 63;
#pragma unroll
  for (int it = 0; it < 16; ++it) {
    int r = it * 4 + lr;
    tile[r][lc] = src[(size_t)(k0 + r) * 1024 + j0 + lc];
  }
  __syncthreads();
  u16* dst = (mat == 3) ? wt_o : (wt_qkv + (size_t)mat * 1024 * 1024);
#pragma unroll
  for (int it = 0; it < 16; ++it) {
    int nl = it * 4 + lr;
    float v = tile[lc][nl];
    if (mat == 0) v *= SCALE_L2E;  // fold attention scale + log2(e)
    dst[(size_t)(j0 + nl) * 1024 + k0 + lc] = f2bf(v);
  }
}

// ---------------------------------------------------------------------------
// gemm_qkv (R21): fused QKV GEMM, 128x256 tile, BK=32, TRIPLE-buffered
// counted-vmcnt pipeline, XOR-swizzled LDS. Grid 768 (balanced).
// 512 thr = 8 waves (2M x 4N); per-wave 64x64 out = acc[4][4].
// LDS: 3 bufs x (A 8KB + B 16KB) = 72KB -> 2 blocks/CU.
// Swizzle (R20-verified): stage source chunk (i&3)^((i>>3)&3); read pos
// (lane>>4)^((fr>>1)&3). 2-way conflicts (free).
// Pipeline: tile t in b[t%3]. Per iter: stage t+2; compute t; vmcnt(3)
// (own t+1 landed, FIFO); raw s_barrier (all waves' t+1 landed). No drain.
// Epilogue: mat uniform per block. Q,K row-major bf16; V fragment-direct
// image (same formula as R17).
// ---------------------------------------------------------------------------
__global__ __launch_bounds__(512, 4) void gemm_qkv(
    const u16* __restrict__ A, const u16* __restrict__ Bt,
    const float* __restrict__ bias0, const float* __restrict__ bias1,
    const float* __restrict__ bias2,
    u16* __restrict__ outQ, u16* __restrict__ outK, u16* __restrict__ outV) {
  __shared__ u16 lA[3][128 * 32];  // [buf][m][k(32)] 8KB each
  __shared__ u16 lB[3][256 * 32];  // [buf][n][k(32)] 16KB each
  int tid = threadIdx.x;
  int wave = tid >> 6, lane = tid & 63;
  int wr = wave >> 2, wc = wave & 3;  // 2M x 4N wave grid

  int bid = blockIdx.x;
  int xcd = bid & 7, j = bid >> 3;          // j 0..95
  int m0 = (xcd * 8 + (j & 7)) * 128;       // m-tiles 0..63 (bijective)
  int n0 = (j >> 3) * 256;                  // n-tiles 0..11

  f32x4 acc[4][4];
#pragma unroll
  for (int fm = 0; fm < 4; ++fm)
#pragma unroll
    for (int fn = 0; fn < 4; ++fn) acc[fm][fn] = f32x4{0.f, 0.f, 0.f, 0.f};

  int srow = lane >> 2;                               // 0..15 within a DMA
  int schunk = ((lane & 3) ^ ((lane >> 3) & 3)) * 8;  // source chunk (elems)
  int fr = lane & 15;
  int rpos = (((lane >> 4) ^ ((fr >> 1) & 3))) * 8;   // read pos (elems)

  const u16* Asrc = A + (size_t)(m0 + wave * 16 + srow) * 1024 + schunk;
  const u16* Bsrc0 = Bt + (size_t)(n0 + wave * 32 + srow) * 1024 + schunk;
  const u16* Bsrc1 = Bsrc0 + (size_t)16 * 1024;

  // prologue: stage tiles 0,1 into bufs 0,1; wait own tile-0 loads; barrier
  gld_lds16(Asrc, &lA[0][wave * 16 * 32]);
  gld_lds16(Bsrc0, &lB[0][wave * 32 * 32]);
  gld_lds16(Bsrc1, &lB[0][(wave * 32 + 16) * 32]);
  gld_lds16(Asrc + 32, &lA[1][wave * 16 * 32]);
  gld_lds16(Bsrc0 + 32, &lB[1][wave * 32 * 32]);
  gld_lds16(Bsrc1 + 32, &lB[1][(wave * 32 + 16) * 32]);
  asm volatile("s_waitcnt vmcnt(3)" ::: "memory");  // tile 0 landed (mine)
  __builtin_amdgcn_s_barrier();                     // everyone's tile 0 landed
  asm volatile("" ::: "memory");                    // pin loads below barrier

  int bR = 0;  // read buffer (tile kt); stage target = (bR+2)%3
  for (int kt = 0; kt < 32; ++kt) {
    int bS = bR + 2; if (bS >= 3) bS -= 3;
    if (kt + 2 < 32) {
      // stage tile kt+2; its buffer's readers finished at barrier kt-1
      int k1 = (kt + 2) * 32;
      gld_lds16(Asrc + k1, &lA[bS][wave * 16 * 32]);
      gld_lds16(Bsrc0 + k1, &lB[bS][wave * 32 * 32]);
      gld_lds16(Bsrc1 + k1, &lB[bS][(wave * 32 + 16) * 32]);
    }
    bf16x8 af[4], bfv[4];
#pragma unroll
    for (int fm = 0; fm < 4; ++fm)
      af[fm] = *(const bf16x8*)(&lA[bR][(wr * 64 + fm * 16 + fr) * 32 + rpos]);
#pragma unroll
    for (int fn = 0; fn < 4; ++fn)
      bfv[fn] = *(const bf16x8*)(&lB[bR][(wc * 64 + fn * 16 + fr) * 32 + rpos]);
    __builtin_amdgcn_s_setprio(1);
#pragma unroll
    for (int fm = 0; fm < 4; ++fm)
#pragma unroll
      for (int fn = 0; fn < 4; ++fn)
        acc[fm][fn] = __builtin_amdgcn_mfma_f32_16x16x32_bf16(
            af[fm], bfv[fn], acc[fm][fn], 0, 0, 0);
    __builtin_amdgcn_s_setprio(0);
    if (kt + 2 < 32) {
      asm volatile("s_waitcnt vmcnt(3)" ::: "memory");  // own kt+1 landed
    } else {
      asm volatile("s_waitcnt vmcnt(0)" ::: "memory");  // tail drain
    }
    __builtin_amdgcn_s_barrier();   // ALL waves' kt+1 landed; kt reads done
    asm volatile("" ::: "memory");  // pin next iter's loads below barrier
    bR = (bR == 2) ? 0 : bR + 1;
  }

  // epilogue: C/D map row=(lane>>4)*4+rr, col=lane&15 (m89-verified)
  int mat = n0 >> 10;  // block entirely within one of Q/K/V (256 | 1024)
  const float* bp = (mat == 0) ? bias0 : (mat == 1) ? bias1 : bias2;
  int rb0 = m0 + wr * 64 + (lane >> 4) * 4;
  int jb = (n0 & 1023) + wc * 64;
#pragma unroll
  for (int fn = 0; fn < 4; ++fn) {
    int jj = jb + fn * 16 + fr;
    float bv = bp[jj];
    if (mat == 0) bv *= SCALE_L2E;
    if (mat == 2) {
      // V fragment-direct image (same formula as R17 epilogue)
      int h = jj >> 6, hd = jj & 63;
#pragma unroll
      for (int fm = 0; fm < 4; ++fm) {
        int row0 = rb0 + fm * 16;  // multiple of 4, no b/s crossing
        int b = row0 >> 11, s = row0 & 2047;
        int ci = s >> 6, sl = s & 63;
        int slice = sl >> 4, srem = sl & 15;   // srem in {0,4,8,12}
        size_t off = (size_t)(b * 16 + h) * 131072 + ci * 4096 + slice * 1024
                   + ((srem >> 2) & 1) * 512 + hd * 8 + (srem >> 3) * 4;
        ushort4 pk;
        pk.x = f2bf_fast(acc[fm][fn][0] + bv);
        pk.y = f2bf_fast(acc[fm][fn][1] + bv);
        pk.z = f2bf_fast(acc[fm][fn][2] + bv);
        pk.w = f2bf_fast(acc[fm][fn][3] + bv);
        *(ushort4*)(outV + off) = pk;
      }
    } else {
      u16* base = (mat == 0) ? outQ : outK;
#pragma unroll
      for (int fm = 0; fm < 4; ++fm)
#pragma unroll
        for (int rr = 0; rr < 4; ++rr)
          base[(size_t)(rb0 + fm * 16 + rr) * 1024 + jj] =
              f2bf_fast(acc[fm][fn][rr] + bv);
    }
  }
}

// ---------------------------------------------------------------------------
// GEMM (old m97-style 128^2; used for MODE 1 only): C = A x Bt^T + bias.
// 4 waves 2x2, 4x4 of 16x16x32 MFMA; XCD-swizzled. 512 blocks, balanced.
// ---------------------------------------------------------------------------
template <int MODE>
__global__ __launch_bounds__(256, 3) void gemm_bt(
    const u16* __restrict__ A, const u16* __restrict__ Bt,
    const float* __restrict__ bias0, const float* __restrict__ bias1,
    const float* __restrict__ bias2,
    void* __restrict__ out0v, void* __restrict__ out1v, void* __restrict__ out2v) {
  __shared__ u16 lA[128 * 32];  // [m][k] rows of 32 bf16 (64B)
  __shared__ u16 lB[128 * 32];  // [n][k]
  const int K = 1024;
  int tid = threadIdx.x;
  int wave = tid >> 6, lane = tid & 63;

  int bid = blockIdx.x;
  int n0 = (bid & 7) * 128;                 // XCD owns 1 n-tile (256KB B)
  int m0 = (bid >> 3) * 128;
  int wm = (wave & 1) * 64, wn = (wave >> 1) * 64;

  f32x4 acc[4][4];
#pragma unroll
  for (int i = 0; i < 4; ++i)
#pragma unroll
    for (int jj = 0; jj < 4; ++jj) acc[i][jj] = f32x4{0.f, 0.f, 0.f, 0.f};

  int srow = lane >> 2;          // source row within 16-row stage
  int scol = (lane & 3) * 8;     // source col chunk within 32

  for (int k0 = 0; k0 < K; k0 += 32) {
#pragma unroll
    for (int c = 0; c < 2; ++c) {
      int rbase = wave * 32 + c * 16;
      gld_lds16(A + (size_t)(m0 + rbase + srow) * K + k0 + scol, lA + rbase * 32);
      gld_lds16(Bt + (size_t)(n0 + rbase + srow) * K + k0 + scol, lB + rbase * 32);
    }
    __syncthreads();
    bf16x8 af[4], bfr[4];
#pragma unroll
    for (int mt = 0; mt < 4; ++mt)
      af[mt] = *(const bf16x8*)(lA + (wm + mt * 16 + (lane & 15)) * 32 + (lane >> 4) * 8);
#pragma unroll
    for (int nt = 0; nt < 4; ++nt)
      bfr[nt] = *(const bf16x8*)(lB + (wn + nt * 16 + (lane & 15)) * 32 + (lane >> 4) * 8);
#pragma unroll
    for (int mt = 0; mt < 4; ++mt)
#pragma unroll
      for (int nt = 0; nt < 4; ++nt)
        acc[mt][nt] = __builtin_amdgcn_mfma_f32_16x16x32_bf16(af[mt], bfr[nt], acc[mt][nt], 0, 0, 0);
    __syncthreads();
  }

  // epilogue: C/D layout row=(lane>>4)*4+r, col=lane&15 (m89-verified)
  int rbase0 = m0 + wm + (lane >> 4) * 4;
  int cbase = n0 + wn + (lane & 15);
#pragma unroll
  for (int nt = 0; nt < 4; ++nt) {
    int col = cbase + nt * 16;
    float bv = bias0[col];
    float* o = (float*)out0v;
#pragma unroll
    for (int mt = 0; mt < 4; ++mt)
#pragma unroll
      for (int r = 0; r < 4; ++r) {
        int row = rbase0 + mt * 16 + r;
        o[(size_t)row * 1024 + col] = acc[mt][nt][r] + bv;
      }
  }
}

// ---------------------------------------------------------------------------
// Flash attention (R17, FROZEN): 32x32x16 MFMA + T14 async reg-staging +
// 64 q/wave + fragment-direct V image (b128 PV reads).
// Grid 256 (1 block/CU): block = (bh, 512 q-rows), 8 waves x 64 q.
// ---------------------------------------------------------------------------
__global__ __launch_bounds__(512, 2) void flash_attn(
    const u16* __restrict__ Q, const u16* __restrict__ Kb,
    const u16* __restrict__ Vg, u16* __restrict__ ctx) {
  __shared__ u16 lK[2][64 * 32];  // [k-half][kv-row][32] xor-swizzled (8KB)
  __shared__ u16 lV[4096];        // fragment-direct image [slice][hi][d][8] (8KB)
  int tid = threadIdx.x, wave = tid >> 6, lane = tid & 63;  // wave 0..7

  int F = blockIdx.x;             // 256 flat blocks
  int xcd = F & 7, idx = F >> 3;  // 32 per XCD
  int bh = xcd * 8 + (idx >> 2);  // 8 bh per XCD; q-blocks of a bh adjacent
  int q0 = (idx & 3) * 512;
  int b = bh >> 4, h = bh & 15;
  const u16* Qp = Q + (size_t)b * 2048 * 1024 + h * 64;   // row-major head slice
  const u16* Kp = Kb + (size_t)b * 2048 * 1024 + h * 64;
  const u16* Vp = Vg + (size_t)bh * 131072;

  int ql = lane & 31;   // q (and K-row / V-d row) within 32-block
  int hi = lane >> 5;   // lane half

  // Q B-fragments (persistent): qf[qt][kk] = Q[q0+wave*64+qt*32+ql][kk*16+hi*8+j]
  bf16x8 qf[2][4];
#pragma unroll
  for (int qt = 0; qt < 2; ++qt) {
    const u16* qrow = Qp + (size_t)(q0 + wave * 64 + qt * 32 + ql) * 1024;
#pragma unroll
    for (int kk = 0; kk < 4; ++kk)
      qf[qt][kk] = *(const bf16x8*)(qrow + kk * 16 + hi * 8);
  }

  float lsum[2] = {0.f, 0.f};
  f32x16 o[2][2];  // [qt][dh]: O^T row d=32*dh+(r&3)+8*(r>>2)+4*hi, col q=ql
#pragma unroll
  for (int qt = 0; qt < 2; ++qt)
#pragma unroll
    for (int dh = 0; dh < 2; ++dh) o[qt][dh] = zero16();

  // Staging (T14 reg-staged; split over 8 waves):
  int srow = lane >> 2;
  int schunk = (((lane & 3) ^ ((lane >> 3) & 3)) * 8);
  int kk_w = wave & 1;
  int rb = wave >> 1;      // 0..3
  int stg_row = rb * 16 + srow;
  int rkey = ((lane & 15) >> 1) & 3;  // read-side swizzle key (row%16 == lane&15)

  const u16* gK = Kp + (size_t)stg_row * 1024 + kk_w * 32 + schunk;  // +s0*1024
  const u16* gV = Vp + wave * 512 + lane * 8;                        // +s0*64
  u16* wK = lK[kk_w] + rb * 512 + lane * 8;  // lane's 16B at base+lane*16 (u16*8)
  u16* wV = lV + wave * 512 + lane * 8;

  // prologue: tile 0 regs -> LDS
  i32x4 ldK = *(const i32x4*)gK;
  i32x4 ldV = *(const i32x4*)gV;
  *(i32x4*)wK = ldK;
  *(i32x4*)wV = ldV;
  __syncthreads();

  for (int s0 = 0; s0 < 2048; s0 += 64) {
    bool more = (s0 + 64 < 2048);  // wave-uniform
    if (more) {
      // issue t+1 loads now; latency hides under compute(t)
      ldK = *(const i32x4*)(gK + (size_t)(s0 + 64) * 1024);
      ldV = *(const i32x4*)(gV + (size_t)(s0 + 64) * 64);
    }

#pragma unroll
    for (int sb = 0; sb < 2; ++sb) {
      // K A-fragments (read once, feed both q-tiles):
      bf16x8 kf[4];
      int krb = (sb * 32 + ql) * 32;  // row base (u16)
#pragma unroll
      for (int kk = 0; kk < 4; ++kk)
        kf[kk] = *(const bf16x8*)(lK[kk >> 1] + krb + ((((kk & 1) << 1) | hi) ^ rkey) * 8);

      f32x16 sa0 = zero16(), sa1 = zero16();
#pragma unroll
      for (int kk = 0; kk < 4; ++kk) {
        sa0 = __builtin_amdgcn_mfma_f32_32x32x16_bf16(kf[kk], qf[0][kk], sa0, 0, 0, 0);
        sa1 = __builtin_amdgcn_mfma_f32_32x32x16_bf16(kf[kk], qf[1][kk], sa1, 0, 0, 0);
      }

      // softmax (fixed max 0, log2 units): reg r -> s_local = (r&3)+8*(r>>2)+4*hi
      bf16x8 pu[2][2];
#pragma unroll
      for (int qt = 0; qt < 2; ++qt) {
        float p[16];
#pragma unroll
        for (int r = 0; r < 16; ++r)
          p[r] = exp2_fast(qt == 0 ? sa0[r] : sa1[r]);
        float a0 = (p[0] + p[1]) + (p[2] + p[3]);
        float a1 = (p[4] + p[5]) + (p[6] + p[7]);
        float a2 = (p[8] + p[9]) + (p[10] + p[11]);
        float a3 = (p[12] + p[13]) + (p[14] + p[15]);
        lsum[qt] += (a0 + a1) + (a2 + a3);
#pragma unroll
        for (int ss = 0; ss < 2; ++ss) {
          union { u32 w[4]; bf16x8 v; } pk_;
          pk_.w[0] = pk2(p[8 * ss + 0], p[8 * ss + 1]);
          pk_.w[1] = pk2(p[8 * ss + 2], p[8 * ss + 3]);
          pk_.w[2] = pk2(p[8 * ss + 4], p[8 * ss + 5]);
          pk_.w[3] = pk2(p[8 * ss + 6], p[8 * ss + 7]);
          pu[qt][ss] = pk_.v;
        }
      }

      // PV: per 16-s slice ss, per d-half dh: ONE b128 A-frag read from the
      // fragment-direct image (pi-order k-slots match register-native P).
#pragma unroll
      for (int ss = 0; ss < 2; ++ss) {
        int vbase = (sb * 2 + ss) * 1024 + hi * 512 + ql * 8;
#pragma unroll
        for (int dh = 0; dh < 2; ++dh) {
          bf16x8 vf = *(const bf16x8*)(lV + vbase + dh * 256);
          o[0][dh] = __builtin_amdgcn_mfma_f32_32x32x16_bf16(vf, pu[0][ss], o[0][dh], 0, 0, 0);
          o[1][dh] = __builtin_amdgcn_mfma_f32_32x32x16_bf16(vf, pu[1][ss], o[1][dh], 0, 0, 0);
        }
      }
    }

    __syncthreads();   // all waves done reading tile t; t+1 loads retired
    if (more) {
      *(i32x4*)wK = ldK;
      *(i32x4*)wV = ldV;
    }
    __syncthreads();   // t+1 LDS writes visible
  }

  // epilogue: lsum pairs live on lanes l and l^32 (same q) -> one shfl_xor;
  // normalize, write ctx[b][q][h][d], d = 32*dh + 8*(r>>2) + 4*hi + (r&3)
#pragma unroll
  for (int qt = 0; qt < 2; ++qt) {
    float rs = lsum[qt] + __shfl_xor(lsum[qt], 32);
    float inv = 1.0f / fmaxf(rs, 1e-30f);
    int q = q0 + wave * 64 + qt * 32 + ql;
    size_t rowbase = ((size_t)(b * 2048 + q) * 16 + h) * 64;
#pragma unroll
    for (int dh = 0; dh < 2; ++dh)
#pragma unroll
      for (int rr = 0; rr < 4; ++rr) {
        ushort4 pk;
        pk.x = f2bf_fast(o[qt][dh][4 * rr + 0] * inv);
        pk.y = f2bf_fast(o[qt][dh][4 * rr + 1] * inv);
        pk.z = f2bf_fast(o[qt][dh][4 * rr + 2] * inv);
        pk.w = f2bf_fast(o[qt][dh][4 * rr + 3] * inv);
        *(ushort4*)(ctx + rowbase + dh * 32 + rr * 8 + hi * 4) = pk;
      }
  }
}

// ---------------------------------------------------------------------------
extern "C" void kernel_launch(void* const* d_in, const int* in_sizes, int n_in,
                              void* d_out, int out_size, void* d_ws, size_t ws_size,
                              hipStream_t stream) {
  const float* x  = (const float*)d_in[0];
  const float* wq = (const float*)d_in[1];
  const float* bq = (const float*)d_in[2];
  const float* wk = (const float*)d_in[3];
  const float* bk = (const float*)d_in[4];
  const float* wv = (const float*)d_in[5];
  const float* bv = (const float*)d_in[6];
  const float* wo = (const float*)d_in[7];
  const float* bo = (const float*)d_in[8];

  u16* ws = (u16*)d_ws;
  u16* xb     = ws;                            // 8192*1024 bf16 (16MB)
  u16* wt_qkv = xb + (size_t)8192 * 1024;      // 3072*1024 (6MB)
  u16* wt_o   = wt_qkv + (size_t)3072 * 1024;  // 1024*1024 (2MB)
  u16* Qb     = wt_o + (size_t)1024 * 1024;    // row-major [B,S,D] (16MB)
  u16* Kbuf   = Qb + (size_t)8192 * 1024;      // row-major [B,S,D] (16MB)
  u16* Vgb    = Kbuf + (size_t)8192 * 1024;    // fragment-direct image (16MB)
  u16* ctx    = Vgb + (size_t)8192 * 1024;     // [B,S,D] bf16 (16MB)
  // total ws use: 88MB

  convert_x<<<8192, 256, 0, stream>>>(x, xb);
  pack_weights<<<dim3(16, 16, 4), 256, 0, stream>>>(wq, wk, wv, wo, wt_qkv, wt_o);
  gemm_qkv<<<768, 512, 0, stream>>>(xb, wt_qkv, bq, bk, bv, Qb, Kbuf, Vgb);
  flash_attn<<<256, 512, 0, stream>>>(Qb, Kbuf, Vgb, ctx);
  gemm_bt<1><<<512, 256, 0, stream>>>(ctx, wt_o, bo, nullptr, nullptr,
                                      d_out, nullptr, nullptr);
}

// Round 15
// 273.594 us; speedup vs baseline: 1.1198x; 1.0196x over previous
//
#include <hip/hip_runtime.h>
#include <stdint.h>

// Problem: B=4, S=2048, D=1024, H=16, HD=64. I/O fp32; internal compute bf16
// MFMA with fp32 accumulation.
// SCALE*log2(e) folded into wq^T and bq -> flash uses exp2 directly with a
// FIXED softmax max of 0 (shift-invariant; logits statically bounded ~|9|).
// Flash: R17 structure FROZEN (~90-94us floor; R13/R14/R16/R17 nulls).
// GEMM lineage: R20 128x256/BK=32 2ph + balance + swizzle = ~78us (660 TF).
// R21 triple-buf counted-vmcnt = NULL total -- but it raised LDS to 72KB ->
// 2 blocks/CU resident vs grid 768 = 3/CU work = 75% residency efficiency
// (R19's imbalance bug reintroduced via LDS). Ambiguity: pipeline +30%
// canceled by imbalance, OR pipeline null. R22 decides.
// R22 (this round): same counted-vmcnt triple-buffer protocol (R21-verified,
// absmax clean) at 128x128/BK=32, 4 waves/256thr: LDS 3x16KB=48KB -> 3
// blocks/CU capacity; grid 64x24=1536 = exactly 6/CU = 2 integral rounds of
// 3 (BALANCED). Per-wave per-tile work identical to R21 (acc[4][4], 16 MFMA,
// 4 DMAs -> vmcnt(4)). Swizzle keys identical. 8 consecutive blocks share a
// 256KB B-panel per XCD. If (a): gemm ~60-68, total ~268. If (b): gemm ~78
// again -> GEMM frozen at the 2ph-class ceiling.
// Flash, gemm_bt<1>, convert, pack frozen.

typedef __attribute__((ext_vector_type(8))) short bf16x8;
typedef __attribute__((ext_vector_type(4))) short bf16x4;
typedef __attribute__((ext_vector_type(4))) float f32x4;
typedef __attribute__((ext_vector_type(16))) float f32x16;
typedef __attribute__((ext_vector_type(4))) int i32x4;
typedef unsigned short u16;
typedef unsigned int u32;

#define AS1 __attribute__((address_space(1)))
#define AS3 __attribute__((address_space(3)))

#define SCALE_L2E 0.18033688011112042f  // 0.125 * log2(e)

__device__ __forceinline__ void gld_lds16(const void* g, void* l) {
  // async global->LDS DMA: lane i's 16B land at (wave-uniform) l + i*16;
  // global source address is per-lane (enables source-preswizzle).
  __builtin_amdgcn_global_load_lds((const AS1 void*)g, (AS3 void*)l, 16, 0, 0);
}

__device__ __forceinline__ u16 f2bf(float f) {
  u32 x = __builtin_bit_cast(u32, f);
  x += 0x7fff + ((x >> 16) & 1);  // RNE
  return (u16)(x >> 16);
}

__device__ __forceinline__ u16 f2bf_fast(float a) {
#if __has_builtin(__builtin_amdgcn_cvt_pk_bf16_f32)
  auto v = __builtin_amdgcn_cvt_pk_bf16_f32(a, a);  // both halves = a: order-immune
  return (u16)(__builtin_bit_cast(u32, v) & 0xffffu);
#else
  return f2bf(a);
#endif
}

__device__ __forceinline__ u32 pk2(float a, float b) {  // lo16=a, hi16=b
#if __has_builtin(__builtin_amdgcn_cvt_pk_bf16_f32)
  return __builtin_bit_cast(u32, __builtin_amdgcn_cvt_pk_bf16_f32(a, b));
#else
  return (u32)f2bf(a) | ((u32)f2bf(b) << 16);
#endif
}

__device__ __forceinline__ float exp2_fast(float x) {
#if __has_builtin(__builtin_amdgcn_exp2f)
  return __builtin_amdgcn_exp2f(x);
#else
  return exp2f(x);
#endif
}

__device__ __forceinline__ f32x16 zero16() {
  f32x16 z;
#pragma unroll
  for (int i = 0; i < 16; ++i) z[i] = 0.f;
  return z;
}

// ---------------------------------------------------------------------------
// fp32 -> bf16 conversion of x (8M elements)
// ---------------------------------------------------------------------------
__global__ __launch_bounds__(256) void convert_x(const float* __restrict__ x,
                                                 u16* __restrict__ xb) {
  int i = (blockIdx.x * 256 + threadIdx.x) * 4;
  float4 v = *(const float4*)(x + i);
  ushort4 o;
  o.x = f2bf(v.x); o.y = f2bf(v.y); o.z = f2bf(v.z); o.w = f2bf(v.w);
  *(ushort4*)(xb + i) = o;
}

// ---------------------------------------------------------------------------
// Weight pack (fp32 [K][N] -> bf16 [N][K]); wq scaled by SCALE*log2(e)
// ---------------------------------------------------------------------------
__global__ __launch_bounds__(256) void pack_weights(
    const float* __restrict__ wq, const float* __restrict__ wk,
    const float* __restrict__ wv, const float* __restrict__ wo,
    u16* __restrict__ wt_qkv, u16* __restrict__ wt_o) {
  __shared__ float tile[64][65];
  int mat = blockIdx.z;
  const float* src = (mat == 0) ? wq : (mat == 1) ? wk : (mat == 2) ? wv : wo;
  int k0 = blockIdx.y * 64, j0 = blockIdx.x * 64;
  int t = threadIdx.x;
  int lr = t >> 6;   // 0..3
  int lc = t & 63;
#pragma unroll
  for (int it = 0; it < 16; ++it) {
    int r = it * 4 + lr;
    tile[r][lc] = src[(size_t)(k0 + r) * 1024 + j0 + lc];
  }
  __syncthreads();
  u16* dst = (mat == 3) ? wt_o : (wt_qkv + (size_t)mat * 1024 * 1024);
#pragma unroll
  for (int it = 0; it < 16; ++it) {
    int nl = it * 4 + lr;
    float v = tile[lc][nl];
    if (mat == 0) v *= SCALE_L2E;  // fold attention scale + log2(e)
    dst[(size_t)(j0 + nl) * 1024 + k0 + lc] = f2bf(v);
  }
}

// ---------------------------------------------------------------------------
// gemm_qkv (R22): fused QKV GEMM, 128x128 tile, BK=32, TRIPLE-buffered
// counted-vmcnt pipeline, XOR-swizzled LDS, BALANCED residency.
// 256 thr = 4 waves (2M x 2N); per-wave 64x64 out = acc[4][4], 16 MFMA/tile.
// LDS: 3 bufs x (A 8KB + B 8KB) = 48KB -> 3 blocks/CU; grid 1536 = 6/CU =
// 2 integral rounds of 3 (balanced; R21's 72KB broke this).
// Swizzle (R20-verified): stage source chunk (i&3)^((i>>3)&3); read pos
// (lane>>4)^((fr>>1)&3). 2-way conflicts (free).
// Pipeline: tile t in b[t%3]. Per iter: stage t+2 (4 DMAs/wave); ds_read+
// 16-MFMA cluster (setprio, T5) on b[t%3]; s_waitcnt vmcnt(4) (own t+1
// landed, FIFO); raw s_barrier (all waves' t+1 landed). No drain in loop.
// XCD map: xcd owns m-tiles xcd*8..+8 x all 24 n-tiles; 8 consecutive bids
// share one 256KB B-panel (L2).
// Epilogue: mat uniform per block (BN=128 | 1024). Q,K row-major bf16;
// V fragment-direct image (same formula as R17).
// ---------------------------------------------------------------------------
__global__ __launch_bounds__(256, 3) void gemm_qkv(
    const u16* __restrict__ A, const u16* __restrict__ Bt,
    const float* __restrict__ bias0, const float* __restrict__ bias1,
    const float* __restrict__ bias2,
    u16* __restrict__ outQ, u16* __restrict__ outK, u16* __restrict__ outV) {
  __shared__ u16 lA[3][128 * 32];  // [buf][m][k(32)] 8KB each
  __shared__ u16 lB[3][128 * 32];  // [buf][n][k(32)] 8KB each
  int tid = threadIdx.x;
  int wave = tid >> 6, lane = tid & 63;
  int wm = (wave & 1) * 64, wn = (wave >> 1) * 64;  // 2M x 2N wave grid

  int bid = blockIdx.x;
  int xcd = bid & 7, j = bid >> 3;          // j 0..191
  int m0 = (xcd * 8 + (j & 7)) * 128;       // m-tiles 0..63 (bijective)
  int n0 = (j >> 3) * 128;                  // n-tiles 0..23

  f32x4 acc[4][4];
#pragma unroll
  for (int fm = 0; fm < 4; ++fm)
#pragma unroll
    for (int fn = 0; fn < 4; ++fn) acc[fm][fn] = f32x4{0.f, 0.f, 0.f, 0.f};

  int srow = lane >> 2;                               // 0..15 within a DMA
  int schunk = ((lane & 3) ^ ((lane >> 3) & 3)) * 8;  // source chunk (elems)
  int fr = lane & 15;
  int rpos = (((lane >> 4) ^ ((fr >> 1) & 3))) * 8;   // read pos (elems)

  // per wave: A rows [wave*32, +32) and B rows [wave*32, +32), 2 DMAs each
  const u16* Asrc = A + (size_t)(m0 + wave * 32 + srow) * 1024 + schunk;
  const u16* Bsrc = Bt + (size_t)(n0 + wave * 32 + srow) * 1024 + schunk;

#define STAGE_QKV(buf, kt)                                                  \
  {                                                                         \
    int ko_ = (kt) * 32;                                                    \
    gld_lds16(Asrc + ko_, &lA[buf][wave * 32 * 32]);                        \
    gld_lds16(Asrc + (size_t)16 * 1024 + ko_, &lA[buf][(wave * 32 + 16) * 32]); \
    gld_lds16(Bsrc + ko_, &lB[buf][wave * 32 * 32]);                        \
    gld_lds16(Bsrc + (size_t)16 * 1024 + ko_, &lB[buf][(wave * 32 + 16) * 32]); \
  }

  // prologue: stage tiles 0,1 into bufs 0,1; wait own tile-0 loads; barrier
  STAGE_QKV(0, 0);
  STAGE_QKV(1, 1);
  asm volatile("s_waitcnt vmcnt(4)" ::: "memory");  // tile 0 landed (mine)
  __builtin_amdgcn_s_barrier();                     // everyone's tile 0 landed
  asm volatile("" ::: "memory");                    // pin loads below barrier

  int bR = 0;  // read buffer (tile kt); stage target = (bR+2)%3
  for (int kt = 0; kt < 32; ++kt) {
    int bS = bR + 2; if (bS >= 3) bS -= 3;
    if (kt + 2 < 32) {
      // stage tile kt+2; its buffer's readers finished at barrier kt-1
      STAGE_QKV(bS, kt + 2);
    }
    bf16x8 af[4], bfv[4];
#pragma unroll
    for (int fm = 0; fm < 4; ++fm)
      af[fm] = *(const bf16x8*)(&lA[bR][(wm + fm * 16 + fr) * 32 + rpos]);
#pragma unroll
    for (int fn = 0; fn < 4; ++fn)
      bfv[fn] = *(const bf16x8*)(&lB[bR][(wn + fn * 16 + fr) * 32 + rpos]);
    __builtin_amdgcn_s_setprio(1);
#pragma unroll
    for (int fm = 0; fm < 4; ++fm)
#pragma unroll
      for (int fn = 0; fn < 4; ++fn)
        acc[fm][fn] = __builtin_amdgcn_mfma_f32_16x16x32_bf16(
            af[fm], bfv[fn], acc[fm][fn], 0, 0, 0);
    __builtin_amdgcn_s_setprio(0);
    if (kt + 2 < 32) {
      asm volatile("s_waitcnt vmcnt(4)" ::: "memory");  // own kt+1 landed
    } else {
      asm volatile("s_waitcnt vmcnt(0)" ::: "memory");  // tail drain
    }
    __builtin_amdgcn_s_barrier();   // ALL waves' kt+1 landed; kt reads done
    asm volatile("" ::: "memory");  // pin next iter's loads below barrier
    bR = (bR == 2) ? 0 : bR + 1;
  }
#undef STAGE_QKV

  // epilogue: C/D map row=(lane>>4)*4+rr, col=lane&15 (m89-verified)
  int mat = n0 >> 10;  // block entirely within one of Q/K/V (128 | 1024)
  const float* bp = (mat == 0) ? bias0 : (mat == 1) ? bias1 : bias2;
  int rb0 = m0 + wm + (lane >> 4) * 4;
  int jb = (n0 & 1023) + wn;
#pragma unroll
  for (int fn = 0; fn < 4; ++fn) {
    int jj = jb + fn * 16 + fr;
    float bv = bp[jj];
    if (mat == 0) bv *= SCALE_L2E;
    if (mat == 2) {
      // V fragment-direct image (same formula as R17 epilogue)
      int h = jj >> 6, hd = jj & 63;
#pragma unroll
      for (int fm = 0; fm < 4; ++fm) {
        int row0 = rb0 + fm * 16;  // multiple of 4, no b/s crossing
        int b = row0 >> 11, s = row0 & 2047;
        int ci = s >> 6, sl = s & 63;
        int slice = sl >> 4, srem = sl & 15;   // srem in {0,4,8,12}
        size_t off = (size_t)(b * 16 + h) * 131072 + ci * 4096 + slice * 1024
                   + ((srem >> 2) & 1) * 512 + hd * 8 + (srem >> 3) * 4;
        ushort4 pk;
        pk.x = f2bf_fast(acc[fm][fn][0] + bv);
        pk.y = f2bf_fast(acc[fm][fn][1] + bv);
        pk.z = f2bf_fast(acc[fm][fn][2] + bv);
        pk.w = f2bf_fast(acc[fm][fn][3] + bv);
        *(ushort4*)(outV + off) = pk;
      }
    } else {
      u16* base = (mat == 0) ? outQ : outK;
#pragma unroll
      for (int fm = 0; fm < 4; ++fm)
#pragma unroll
        for (int rr = 0; rr < 4; ++rr)
          base[(size_t)(rb0 + fm * 16 + rr) * 1024 + jj] =
              f2bf_fast(acc[fm][fn][rr] + bv);
    }
  }
}

// ---------------------------------------------------------------------------
// GEMM (old m97-style 128^2; used for MODE 1 only): C = A x Bt^T + bias.
// 4 waves 2x2, 4x4 of 16x16x32 MFMA; XCD-swizzled. 512 blocks, balanced.
// ---------------------------------------------------------------------------
template <int MODE>
__global__ __launch_bounds__(256, 3) void gemm_bt(
    const u16* __restrict__ A, const u16* __restrict__ Bt,
    const float* __restrict__ bias0, const float* __restrict__ bias1,
    const float* __restrict__ bias2,
    void* __restrict__ out0v, void* __restrict__ out1v, void* __restrict__ out2v) {
  __shared__ u16 lA[128 * 32];  // [m][k] rows of 32 bf16 (64B)
  __shared__ u16 lB[128 * 32];  // [n][k]
  const int K = 1024;
  int tid = threadIdx.x;
  int wave = tid >> 6, lane = tid & 63;

  int bid = blockIdx.x;
  int n0 = (bid & 7) * 128;                 // XCD owns 1 n-tile (256KB B)
  int m0 = (bid >> 3) * 128;
  int wm = (wave & 1) * 64, wn = (wave >> 1) * 64;

  f32x4 acc[4][4];
#pragma unroll
  for (int i = 0; i < 4; ++i)
#pragma unroll
    for (int jj = 0; jj < 4; ++jj) acc[i][jj] = f32x4{0.f, 0.f, 0.f, 0.f};

  int srow = lane >> 2;          // source row within 16-row stage
  int scol = (lane & 3) * 8;     // source col chunk within 32

  for (int k0 = 0; k0 < K; k0 += 32) {
#pragma unroll
    for (int c = 0; c < 2; ++c) {
      int rbase = wave * 32 + c * 16;
      gld_lds16(A + (size_t)(m0 + rbase + srow) * K + k0 + scol, lA + rbase * 32);
      gld_lds16(Bt + (size_t)(n0 + rbase + srow) * K + k0 + scol, lB + rbase * 32);
    }
    __syncthreads();
    bf16x8 af[4], bfr[4];
#pragma unroll
    for (int mt = 0; mt < 4; ++mt)
      af[mt] = *(const bf16x8*)(lA + (wm + mt * 16 + (lane & 15)) * 32 + (lane >> 4) * 8);
#pragma unroll
    for (int nt = 0; nt < 4; ++nt)
      bfr[nt] = *(const bf16x8*)(lB + (wn + nt * 16 + (lane & 15)) * 32 + (lane >> 4) * 8);
#pragma unroll
    for (int mt = 0; mt < 4; ++mt)
#pragma unroll
      for (int nt = 0; nt < 4; ++nt)
        acc[mt][nt] = __builtin_amdgcn_mfma_f32_16x16x32_bf16(af[mt], bfr[nt], acc[mt][nt], 0, 0, 0);
    __syncthreads();
  }

  // epilogue: C/D layout row=(lane>>4)*4+r, col=lane&15 (m89-verified)
  int rbase0 = m0 + wm + (lane >> 4) * 4;
  int cbase = n0 + wn + (lane & 15);
#pragma unroll
  for (int nt = 0; nt < 4; ++nt) {
    int col = cbase + nt * 16;
    float bv = bias0[col];
    float* o = (float*)out0v;
#pragma unroll
    for (int mt = 0; mt < 4; ++mt)
#pragma unroll
      for (int r = 0; r < 4; ++r) {
        int row = rbase0 + mt * 16 + r;
        o[(size_t)row * 1024 + col] = acc[mt][nt][r] + bv;
      }
  }
}

// ---------------------------------------------------------------------------
// Flash attention (R17, FROZEN): 32x32x16 MFMA + T14 async reg-staging +
// 64 q/wave + fragment-direct V image (b128 PV reads).
// Grid 256 (1 block/CU): block = (bh, 512 q-rows), 8 waves x 64 q.
// ---------------------------------------------------------------------------
__global__ __launch_bounds__(512, 2) void flash_attn(
    const u16* __restrict__ Q, const u16* __restrict__ Kb,
    const u16* __restrict__ Vg, u16* __restrict__ ctx) {
  __shared__ u16 lK[2][64 * 32];  // [k-half][kv-row][32] xor-swizzled (8KB)
  __shared__ u16 lV[4096];        // fragment-direct image [slice][hi][d][8] (8KB)
  int tid = threadIdx.x, wave = tid >> 6, lane = tid & 63;  // wave 0..7

  int F = blockIdx.x;             // 256 flat blocks
  int xcd = F & 7, idx = F >> 3;  // 32 per XCD
  int bh = xcd * 8 + (idx >> 2);  // 8 bh per XCD; q-blocks of a bh adjacent
  int q0 = (idx & 3) * 512;
  int b = bh >> 4, h = bh & 15;
  const u16* Qp = Q + (size_t)b * 2048 * 1024 + h * 64;   // row-major head slice
  const u16* Kp = Kb + (size_t)b * 2048 * 1024 + h * 64;
  const u16* Vp = Vg + (size_t)bh * 131072;

  int ql = lane & 31;   // q (and K-row / V-d row) within 32-block
  int hi = lane >> 5;   // lane half

  // Q B-fragments (persistent): qf[qt][kk] = Q[q0+wave*64+qt*32+ql][kk*16+hi*8+j]
  bf16x8 qf[2][4];
#pragma unroll
  for (int qt = 0; qt < 2; ++qt) {
    const u16* qrow = Qp + (size_t)(q0 + wave * 64 + qt * 32 + ql) * 1024;
#pragma unroll
    for (int kk = 0; kk < 4; ++kk)
      qf[qt][kk] = *(const bf16x8*)(qrow + kk * 16 + hi * 8);
  }

  float lsum[2] = {0.f, 0.f};
  f32x16 o[2][2];  // [qt][dh]: O^T row d=32*dh+(r&3)+8*(r>>2)+4*hi, col q=ql
#pragma unroll
  for (int qt = 0; qt < 2; ++qt)
#pragma unroll
    for (int dh = 0; dh < 2; ++dh) o[qt][dh] = zero16();

  // Staging (T14 reg-staged; split over 8 waves):
  int srow = lane >> 2;
  int schunk = (((lane & 3) ^ ((lane >> 3) & 3)) * 8);
  int kk_w = wave & 1;
  int rb = wave >> 1;      // 0..3
  int stg_row = rb * 16 + srow;
  int rkey = ((lane & 15) >> 1) & 3;  // read-side swizzle key (row%16 == lane&15)

  const u16* gK = Kp + (size_t)stg_row * 1024 + kk_w * 32 + schunk;  // +s0*1024
  const u16* gV = Vp + wave * 512 + lane * 8;                        // +s0*64
  u16* wK = lK[kk_w] + rb * 512 + lane * 8;  // lane's 16B at base+lane*16 (u16*8)
  u16* wV = lV + wave * 512 + lane * 8;

  // prologue: tile 0 regs -> LDS
  i32x4 ldK = *(const i32x4*)gK;
  i32x4 ldV = *(const i32x4*)gV;
  *(i32x4*)wK = ldK;
  *(i32x4*)wV = ldV;
  __syncthreads();

  for (int s0 = 0; s0 < 2048; s0 += 64) {
    bool more = (s0 + 64 < 2048);  // wave-uniform
    if (more) {
      // issue t+1 loads now; latency hides under compute(t)
      ldK = *(const i32x4*)(gK + (size_t)(s0 + 64) * 1024);
      ldV = *(const i32x4*)(gV + (size_t)(s0 + 64) * 64);
    }

#pragma unroll
    for (int sb = 0; sb < 2; ++sb) {
      // K A-fragments (read once, feed both q-tiles):
      bf16x8 kf[4];
      int krb = (sb * 32 + ql) * 32;  // row base (u16)
#pragma unroll
      for (int kk = 0; kk < 4; ++kk)
        kf[kk] = *(const bf16x8*)(lK[kk >> 1] + krb + ((((kk & 1) << 1) | hi) ^ rkey) * 8);

      f32x16 sa0 = zero16(), sa1 = zero16();
#pragma unroll
      for (int kk = 0; kk < 4; ++kk) {
        sa0 = __builtin_amdgcn_mfma_f32_32x32x16_bf16(kf[kk], qf[0][kk], sa0, 0, 0, 0);
        sa1 = __builtin_amdgcn_mfma_f32_32x32x16_bf16(kf[kk], qf[1][kk], sa1, 0, 0, 0);
      }

      // softmax (fixed max 0, log2 units): reg r -> s_local = (r&3)+8*(r>>2)+4*hi
      bf16x8 pu[2][2];
#pragma unroll
      for (int qt = 0; qt < 2; ++qt) {
        float p[16];
#pragma unroll
        for (int r = 0; r < 16; ++r)
          p[r] = exp2_fast(qt == 0 ? sa0[r] : sa1[r]);
        float a0 = (p[0] + p[1]) + (p[2] + p[3]);
        float a1 = (p[4] + p[5]) + (p[6] + p[7]);
        float a2 = (p[8] + p[9]) + (p[10] + p[11]);
        float a3 = (p[12] + p[13]) + (p[14] + p[15]);
        lsum[qt] += (a0 + a1) + (a2 + a3);
#pragma unroll
        for (int ss = 0; ss < 2; ++ss) {
          union { u32 w[4]; bf16x8 v; } pk_;
          pk_.w[0] = pk2(p[8 * ss + 0], p[8 * ss + 1]);
          pk_.w[1] = pk2(p[8 * ss + 2], p[8 * ss + 3]);
          pk_.w[2] = pk2(p[8 * ss + 4], p[8 * ss + 5]);
          pk_.w[3] = pk2(p[8 * ss + 6], p[8 * ss + 7]);
          pu[qt][ss] = pk_.v;
        }
      }

      // PV: per 16-s slice ss, per d-half dh: ONE b128 A-frag read from the
      // fragment-direct image (pi-order k-slots match register-native P).
#pragma unroll
      for (int ss = 0; ss < 2; ++ss) {
        int vbase = (sb * 2 + ss) * 1024 + hi * 512 + ql * 8;
#pragma unroll
        for (int dh = 0; dh < 2; ++dh) {
          bf16x8 vf = *(const bf16x8*)(lV + vbase + dh * 256);
          o[0][dh] = __builtin_amdgcn_mfma_f32_32x32x16_bf16(vf, pu[0][ss], o[0][dh], 0, 0, 0);
          o[1][dh] = __builtin_amdgcn_mfma_f32_32x32x16_bf16(vf, pu[1][ss], o[1][dh], 0, 0, 0);
        }
      }
    }

    __syncthreads();   // all waves done reading tile t; t+1 loads retired
    if (more) {
      *(i32x4*)wK = ldK;
      *(i32x4*)wV = ldV;
    }
    __syncthreads();   // t+1 LDS writes visible
  }

  // epilogue: lsum pairs live on lanes l and l^32 (same q) -> one shfl_xor;
  // normalize, write ctx[b][q][h][d], d = 32*dh + 8*(r>>2) + 4*hi + (r&3)
#pragma unroll
  for (int qt = 0; qt < 2; ++qt) {
    float rs = lsum[qt] + __shfl_xor(lsum[qt], 32);
    float inv = 1.0f / fmaxf(rs, 1e-30f);
    int q = q0 + wave * 64 + qt * 32 + ql;
    size_t rowbase = ((size_t)(b * 2048 + q) * 16 + h) * 64;
#pragma unroll
    for (int dh = 0; dh < 2; ++dh)
#pragma unroll
      for (int rr = 0; rr < 4; ++rr) {
        ushort4 pk;
        pk.x = f2bf_fast(o[qt][dh][4 * rr + 0] * inv);
        pk.y = f2bf_fast(o[qt][dh][4 * rr + 1] * inv);
        pk.z = f2bf_fast(o[qt][dh][4 * rr + 2] * inv);
        pk.w = f2bf_fast(o[qt][dh][4 * rr + 3] * inv);
        *(ushort4*)(ctx + rowbase + dh * 32 + rr * 8 + hi * 4) = pk;
      }
  }
}

// ---------------------------------------------------------------------------
extern "C" void kernel_launch(void* const* d_in, const int* in_sizes, int n_in,
                              void* d_out, int out_size, void* d_ws, size_t ws_size,
                              hipStream_t stream) {
  const float* x  = (const float*)d_in[0];
  const float* wq = (const float*)d_in[1];
  const float* bq = (const float*)d_in[2];
  const float* wk = (const float*)d_in[3];
  const float* bk = (const float*)d_in[4];
  const float* wv = (const float*)d_in[5];
  const float* bv = (const float*)d_in[6];
  const float* wo = (const float*)d_in[7];
  const float* bo = (const float*)d_in[8];

  u16* ws = (u16*)d_ws;
  u16* xb     = ws;                            // 8192*1024 bf16 (16MB)
  u16* wt_qkv = xb + (size_t)8192 * 1024;      // 3072*1024 (6MB)
  u16* wt_o   = wt_qkv + (size_t)3072 * 1024;  // 1024*1024 (2MB)
  u16* Qb     = wt_o + (size_t)1024 * 1024;    // row-major [B,S,D] (16MB)
  u16* Kbuf   = Qb + (size_t)8192 * 1024;      // row-major [B,S,D] (16MB)
  u16* Vgb    = Kbuf + (size_t)8192 * 1024;    // fragment-direct image (16MB)
  u16* ctx    = Vgb + (size_t)8192 * 1024;     // [B,S,D] bf16 (16MB)
  // total ws use: 88MB

  convert_x<<<8192, 256, 0, stream>>>(x, xb);
  pack_weights<<<dim3(16, 16, 4), 256, 0, stream>>>(wq, wk, wv, wo, wt_qkv, wt_o);
  gemm_qkv<<<1536, 256, 0, stream>>>(xb, wt_qkv, bq, bk, bv, Qb, Kbuf, Vgb);
  flash_attn<<<256, 512, 0, stream>>>(Qb, Kbuf, Vgb, ctx);
  gemm_bt<1><<<512, 256, 0, stream>>>(ctx, wt_o, bo, nullptr, nullptr,
                                      d_out, nullptr, nullptr);
}

// Round 16
// 271.004 us; speedup vs baseline: 1.1305x; 1.0096x over previous
//
#include <hip/hip_runtime.h>
#include <stdint.h>

// Problem: B=4, S=2048, D=1024, H=16, HD=64. I/O fp32; internal compute bf16
// MFMA with fp32 accumulation.
// SCALE*log2(e) folded into wq^T and bq -> flash uses exp2 directly with a
// FIXED softmax max of 0 (shift-invariant; logits statically bounded ~|9|).
// Flash: R17 structure FROZEN (~93us floor; R13/R14/R16/R17 nulls).
// GEMM: R22 counted-vmcnt triple-buffer 128x128/BK=32, balanced residency
// (48KB -> 3 blocks/CU, grid 1536 = 2 integral rounds) = ~71us (~725 TF)
// CONFIRMED (+10% over R20's 2-phase; R21's null was residency imbalance).
// R23 (this round): (1) port the R22-verified pipeline template to the
// output GEMM (gemm_out, was m97-style gemm_bt<1> ~26us/650TF): identical
// loop/swizzle/sync, fp32+bias epilogue, grid 512 = 2/CU integral -> ~23us.
// (2) merge convert_x + pack_weights into one prep kernel (saves one graph
// node). Flash and gemm_qkv byte-identical to R22.

typedef __attribute__((ext_vector_type(8))) short bf16x8;
typedef __attribute__((ext_vector_type(4))) short bf16x4;
typedef __attribute__((ext_vector_type(4))) float f32x4;
typedef __attribute__((ext_vector_type(16))) float f32x16;
typedef __attribute__((ext_vector_type(4))) int i32x4;
typedef unsigned short u16;
typedef unsigned int u32;

#define AS1 __attribute__((address_space(1)))
#define AS3 __attribute__((address_space(3)))

#define SCALE_L2E 0.18033688011112042f  // 0.125 * log2(e)

__device__ __forceinline__ void gld_lds16(const void* g, void* l) {
  // async global->LDS DMA: lane i's 16B land at (wave-uniform) l + i*16;
  // global source address is per-lane (enables source-preswizzle).
  __builtin_amdgcn_global_load_lds((const AS1 void*)g, (AS3 void*)l, 16, 0, 0);
}

__device__ __forceinline__ u16 f2bf(float f) {
  u32 x = __builtin_bit_cast(u32, f);
  x += 0x7fff + ((x >> 16) & 1);  // RNE
  return (u16)(x >> 16);
}

__device__ __forceinline__ u16 f2bf_fast(float a) {
#if __has_builtin(__builtin_amdgcn_cvt_pk_bf16_f32)
  auto v = __builtin_amdgcn_cvt_pk_bf16_f32(a, a);  // both halves = a: order-immune
  return (u16)(__builtin_bit_cast(u32, v) & 0xffffu);
#else
  return f2bf(a);
#endif
}

__device__ __forceinline__ u32 pk2(float a, float b) {  // lo16=a, hi16=b
#if __has_builtin(__builtin_amdgcn_cvt_pk_bf16_f32)
  return __builtin_bit_cast(u32, __builtin_amdgcn_cvt_pk_bf16_f32(a, b));
#else
  return (u32)f2bf(a) | ((u32)f2bf(b) << 16);
#endif
}

__device__ __forceinline__ float exp2_fast(float x) {
#if __has_builtin(__builtin_amdgcn_exp2f)
  return __builtin_amdgcn_exp2f(x);
#else
  return exp2f(x);
#endif
}

__device__ __forceinline__ f32x16 zero16() {
  f32x16 z;
#pragma unroll
  for (int i = 0; i < 16; ++i) z[i] = 0.f;
  return z;
}

// ---------------------------------------------------------------------------
// prep: blocks [0,8192) = fp32->bf16 convert of x (8M elems);
//       blocks [8192,9216) = weight pack (fp32 [K][N] -> bf16 [N][K]),
//       wq scaled by SCALE*log2(e). Decodes the old dim3(16,16,4) grid.
// ---------------------------------------------------------------------------
__global__ __launch_bounds__(256) void prep(
    const float* __restrict__ x, u16* __restrict__ xb,
    const float* __restrict__ wq, const float* __restrict__ wk,
    const float* __restrict__ wv, const float* __restrict__ wo,
    u16* __restrict__ wt_qkv, u16* __restrict__ wt_o) {
  __shared__ float tile[64][65];
  int bid = blockIdx.x;
  if (bid < 8192) {
    int i = (bid * 256 + threadIdx.x) * 4;
    float4 v = *(const float4*)(x + i);
    ushort4 o;
    o.x = f2bf(v.x); o.y = f2bf(v.y); o.z = f2bf(v.z); o.w = f2bf(v.w);
    *(ushort4*)(xb + i) = o;
    return;
  }
  int pb = bid - 8192;             // 0..1023
  int mat = pb >> 8;               // 0..3 (was blockIdx.z)
  int rem = pb & 255;
  int k0 = (rem >> 4) * 64;        // was blockIdx.y*64
  int j0 = (rem & 15) * 64;        // was blockIdx.x*64
  const float* src = (mat == 0) ? wq : (mat == 1) ? wk : (mat == 2) ? wv : wo;
  int t = threadIdx.x;
  int lr = t >> 6;   // 0..3
  int lc = t & 63;
#pragma unroll
  for (int it = 0; it < 16; ++it) {
    int r = it * 4 + lr;
    tile[r][lc] = src[(size_t)(k0 + r) * 1024 + j0 + lc];
  }
  __syncthreads();
  u16* dst = (mat == 3) ? wt_o : (wt_qkv + (size_t)mat * 1024 * 1024);
#pragma unroll
  for (int it = 0; it < 16; ++it) {
    int nl = it * 4 + lr;
    float v = tile[lc][nl];
    if (mat == 0) v *= SCALE_L2E;  // fold attention scale + log2(e)
    dst[(size_t)(j0 + nl) * 1024 + k0 + lc] = f2bf(v);
  }
}

// ---------------------------------------------------------------------------
// gemm_qkv (R22, FROZEN): fused QKV GEMM, 128x128 tile, BK=32, triple-
// buffered counted-vmcnt pipeline, XOR-swizzled LDS, balanced residency.
// 256 thr = 4 waves (2Mx2N); per-wave 64x64 = acc[4][4], 16 MFMA/tile.
// LDS 3x16KB = 48KB -> 3 blocks/CU; grid 1536 = 2 integral rounds of 3.
// Pipeline: stage t+2; compute t (setprio cluster); vmcnt(4); raw s_barrier.
// ---------------------------------------------------------------------------
__global__ __launch_bounds__(256, 3) void gemm_qkv(
    const u16* __restrict__ A, const u16* __restrict__ Bt,
    const float* __restrict__ bias0, const float* __restrict__ bias1,
    const float* __restrict__ bias2,
    u16* __restrict__ outQ, u16* __restrict__ outK, u16* __restrict__ outV) {
  __shared__ u16 lA[3][128 * 32];  // [buf][m][k(32)] 8KB each
  __shared__ u16 lB[3][128 * 32];  // [buf][n][k(32)] 8KB each
  int tid = threadIdx.x;
  int wave = tid >> 6, lane = tid & 63;
  int wm = (wave & 1) * 64, wn = (wave >> 1) * 64;  // 2M x 2N wave grid

  int bid = blockIdx.x;
  int xcd = bid & 7, j = bid >> 3;          // j 0..191
  int m0 = (xcd * 8 + (j & 7)) * 128;       // m-tiles 0..63 (bijective)
  int n0 = (j >> 3) * 128;                  // n-tiles 0..23

  f32x4 acc[4][4];
#pragma unroll
  for (int fm = 0; fm < 4; ++fm)
#pragma unroll
    for (int fn = 0; fn < 4; ++fn) acc[fm][fn] = f32x4{0.f, 0.f, 0.f, 0.f};

  int srow = lane >> 2;                               // 0..15 within a DMA
  int schunk = ((lane & 3) ^ ((lane >> 3) & 3)) * 8;  // source chunk (elems)
  int fr = lane & 15;
  int rpos = (((lane >> 4) ^ ((fr >> 1) & 3))) * 8;   // read pos (elems)

  const u16* Asrc = A + (size_t)(m0 + wave * 32 + srow) * 1024 + schunk;
  const u16* Bsrc = Bt + (size_t)(n0 + wave * 32 + srow) * 1024 + schunk;

#define STAGE_T(buf, kt)                                                    \
  {                                                                         \
    int ko_ = (kt) * 32;                                                    \
    gld_lds16(Asrc + ko_, &lA[buf][wave * 32 * 32]);                        \
    gld_lds16(Asrc + (size_t)16 * 1024 + ko_, &lA[buf][(wave * 32 + 16) * 32]); \
    gld_lds16(Bsrc + ko_, &lB[buf][wave * 32 * 32]);                        \
    gld_lds16(Bsrc + (size_t)16 * 1024 + ko_, &lB[buf][(wave * 32 + 16) * 32]); \
  }

  STAGE_T(0, 0);
  STAGE_T(1, 1);
  asm volatile("s_waitcnt vmcnt(4)" ::: "memory");  // tile 0 landed (mine)
  __builtin_amdgcn_s_barrier();                     // everyone's tile 0 landed
  asm volatile("" ::: "memory");

  int bR = 0;
  for (int kt = 0; kt < 32; ++kt) {
    int bS = bR + 2; if (bS >= 3) bS -= 3;
    if (kt + 2 < 32) STAGE_T(bS, kt + 2);
    bf16x8 af[4], bfv[4];
#pragma unroll
    for (int fm = 0; fm < 4; ++fm)
      af[fm] = *(const bf16x8*)(&lA[bR][(wm + fm * 16 + fr) * 32 + rpos]);
#pragma unroll
    for (int fn = 0; fn < 4; ++fn)
      bfv[fn] = *(const bf16x8*)(&lB[bR][(wn + fn * 16 + fr) * 32 + rpos]);
    __builtin_amdgcn_s_setprio(1);
#pragma unroll
    for (int fm = 0; fm < 4; ++fm)
#pragma unroll
      for (int fn = 0; fn < 4; ++fn)
        acc[fm][fn] = __builtin_amdgcn_mfma_f32_16x16x32_bf16(
            af[fm], bfv[fn], acc[fm][fn], 0, 0, 0);
    __builtin_amdgcn_s_setprio(0);
    if (kt + 2 < 32) {
      asm volatile("s_waitcnt vmcnt(4)" ::: "memory");  // own kt+1 landed
    } else {
      asm volatile("s_waitcnt vmcnt(0)" ::: "memory");  // tail drain
    }
    __builtin_amdgcn_s_barrier();
    asm volatile("" ::: "memory");
    bR = (bR == 2) ? 0 : bR + 1;
  }
#undef STAGE_T

  // epilogue: C/D map row=(lane>>4)*4+rr, col=lane&15 (m89-verified)
  int mat = n0 >> 10;  // block entirely within one of Q/K/V (128 | 1024)
  const float* bp = (mat == 0) ? bias0 : (mat == 1) ? bias1 : bias2;
  int rb0 = m0 + wm + (lane >> 4) * 4;
  int jb = (n0 & 1023) + wn;
#pragma unroll
  for (int fn = 0; fn < 4; ++fn) {
    int jj = jb + fn * 16 + fr;
    float bv = bp[jj];
    if (mat == 0) bv *= SCALE_L2E;
    if (mat == 2) {
      // V fragment-direct image (same formula as R17 epilogue)
      int h = jj >> 6, hd = jj & 63;
#pragma unroll
      for (int fm = 0; fm < 4; ++fm) {
        int row0 = rb0 + fm * 16;  // multiple of 4, no b/s crossing
        int b = row0 >> 11, s = row0 & 2047;
        int ci = s >> 6, sl = s & 63;
        int slice = sl >> 4, srem = sl & 15;   // srem in {0,4,8,12}
        size_t off = (size_t)(b * 16 + h) * 131072 + ci * 4096 + slice * 1024
                   + ((srem >> 2) & 1) * 512 + hd * 8 + (srem >> 3) * 4;
        ushort4 pk;
        pk.x = f2bf_fast(acc[fm][fn][0] + bv);
        pk.y = f2bf_fast(acc[fm][fn][1] + bv);
        pk.z = f2bf_fast(acc[fm][fn][2] + bv);
        pk.w = f2bf_fast(acc[fm][fn][3] + bv);
        *(ushort4*)(outV + off) = pk;
      }
    } else {
      u16* base = (mat == 0) ? outQ : outK;
#pragma unroll
      for (int fm = 0; fm < 4; ++fm)
#pragma unroll
        for (int rr = 0; rr < 4; ++rr)
          base[(size_t)(rb0 + fm * 16 + rr) * 1024 + jj] =
              f2bf_fast(acc[fm][fn][rr] + bv);
    }
  }
}

// ---------------------------------------------------------------------------
// gemm_out (R23): output GEMM d_out = ctx x wt_o^T + bo (fp32 out).
// Same R22 pipeline template: 128x128/BK=32, 4 waves, 3-buf counted-vmcnt,
// XOR swizzle. Grid 512 = 2 blocks/CU integral (48KB -> all resident).
// XCD map: xcd owns m-tiles xcd*8..+8 x all 8 n-tiles (bijective 64x8).
// ---------------------------------------------------------------------------
__global__ __launch_bounds__(256, 3) void gemm_out(
    const u16* __restrict__ A, const u16* __restrict__ Bt,
    const float* __restrict__ bias, float* __restrict__ out) {
  __shared__ u16 lA[3][128 * 32];
  __shared__ u16 lB[3][128 * 32];
  int tid = threadIdx.x;
  int wave = tid >> 6, lane = tid & 63;
  int wm = (wave & 1) * 64, wn = (wave >> 1) * 64;

  int bid = blockIdx.x;
  int xcd = bid & 7, j = bid >> 3;          // j 0..63
  int m0 = (xcd * 8 + (j & 7)) * 128;       // m-tiles 0..63 (bijective)
  int n0 = (j >> 3) * 128;                  // n-tiles 0..7

  f32x4 acc[4][4];
#pragma unroll
  for (int fm = 0; fm < 4; ++fm)
#pragma unroll
    for (int fn = 0; fn < 4; ++fn) acc[fm][fn] = f32x4{0.f, 0.f, 0.f, 0.f};

  int srow = lane >> 2;
  int schunk = ((lane & 3) ^ ((lane >> 3) & 3)) * 8;
  int fr = lane & 15;
  int rpos = (((lane >> 4) ^ ((fr >> 1) & 3))) * 8;

  const u16* Asrc = A + (size_t)(m0 + wave * 32 + srow) * 1024 + schunk;
  const u16* Bsrc = Bt + (size_t)(n0 + wave * 32 + srow) * 1024 + schunk;

#define STAGE_O(buf, kt)                                                    \
  {                                                                         \
    int ko_ = (kt) * 32;                                                    \
    gld_lds16(Asrc + ko_, &lA[buf][wave * 32 * 32]);                        \
    gld_lds16(Asrc + (size_t)16 * 1024 + ko_, &lA[buf][(wave * 32 + 16) * 32]); \
    gld_lds16(Bsrc + ko_, &lB[buf][wave * 32 * 32]);                        \
    gld_lds16(Bsrc + (size_t)16 * 1024 + ko_, &lB[buf][(wave * 32 + 16) * 32]); \
  }

  STAGE_O(0, 0);
  STAGE_O(1, 1);
  asm volatile("s_waitcnt vmcnt(4)" ::: "memory");
  __builtin_amdgcn_s_barrier();
  asm volatile("" ::: "memory");

  int bR = 0;
  for (int kt = 0; kt < 32; ++kt) {
    int bS = bR + 2; if (bS >= 3) bS -= 3;
    if (kt + 2 < 32) STAGE_O(bS, kt + 2);
    bf16x8 af[4], bfv[4];
#pragma unroll
    for (int fm = 0; fm < 4; ++fm)
      af[fm] = *(const bf16x8*)(&lA[bR][(wm + fm * 16 + fr) * 32 + rpos]);
#pragma unroll
    for (int fn = 0; fn < 4; ++fn)
      bfv[fn] = *(const bf16x8*)(&lB[bR][(wn + fn * 16 + fr) * 32 + rpos]);
    __builtin_amdgcn_s_setprio(1);
#pragma unroll
    for (int fm = 0; fm < 4; ++fm)
#pragma unroll
      for (int fn = 0; fn < 4; ++fn)
        acc[fm][fn] = __builtin_amdgcn_mfma_f32_16x16x32_bf16(
            af[fm], bfv[fn], acc[fm][fn], 0, 0, 0);
    __builtin_amdgcn_s_setprio(0);
    if (kt + 2 < 32) {
      asm volatile("s_waitcnt vmcnt(4)" ::: "memory");
    } else {
      asm volatile("s_waitcnt vmcnt(0)" ::: "memory");
    }
    __builtin_amdgcn_s_barrier();
    asm volatile("" ::: "memory");
    bR = (bR == 2) ? 0 : bR + 1;
  }
#undef STAGE_O

  // epilogue: fp32 row-major + bias (coalesced: consecutive fr -> consecutive col)
  int rb0 = m0 + wm + (lane >> 4) * 4;
#pragma unroll
  for (int fn = 0; fn < 4; ++fn) {
    int jj = n0 + wn + fn * 16 + fr;
    float bv = bias[jj];
#pragma unroll
    for (int fm = 0; fm < 4; ++fm)
#pragma unroll
      for (int rr = 0; rr < 4; ++rr)
        out[(size_t)(rb0 + fm * 16 + rr) * 1024 + jj] = acc[fm][fn][rr] + bv;
  }
}

// ---------------------------------------------------------------------------
// Flash attention (R17, FROZEN): 32x32x16 MFMA + T14 async reg-staging +
// 64 q/wave + fragment-direct V image (b128 PV reads).
// Grid 256 (1 block/CU): block = (bh, 512 q-rows), 8 waves x 64 q.
// ---------------------------------------------------------------------------
__global__ __launch_bounds__(512, 2) void flash_attn(
    const u16* __restrict__ Q, const u16* __restrict__ Kb,
    const u16* __restrict__ Vg, u16* __restrict__ ctx) {
  __shared__ u16 lK[2][64 * 32];  // [k-half][kv-row][32] xor-swizzled (8KB)
  __shared__ u16 lV[4096];        // fragment-direct image [slice][hi][d][8] (8KB)
  int tid = threadIdx.x, wave = tid >> 6, lane = tid & 63;  // wave 0..7

  int F = blockIdx.x;             // 256 flat blocks
  int xcd = F & 7, idx = F >> 3;  // 32 per XCD
  int bh = xcd * 8 + (idx >> 2);  // 8 bh per XCD; q-blocks of a bh adjacent
  int q0 = (idx & 3) * 512;
  int b = bh >> 4, h = bh & 15;
  const u16* Qp = Q + (size_t)b * 2048 * 1024 + h * 64;   // row-major head slice
  const u16* Kp = Kb + (size_t)b * 2048 * 1024 + h * 64;
  const u16* Vp = Vg + (size_t)bh * 131072;

  int ql = lane & 31;   // q (and K-row / V-d row) within 32-block
  int hi = lane >> 5;   // lane half

  // Q B-fragments (persistent): qf[qt][kk] = Q[q0+wave*64+qt*32+ql][kk*16+hi*8+j]
  bf16x8 qf[2][4];
#pragma unroll
  for (int qt = 0; qt < 2; ++qt) {
    const u16* qrow = Qp + (size_t)(q0 + wave * 64 + qt * 32 + ql) * 1024;
#pragma unroll
    for (int kk = 0; kk < 4; ++kk)
      qf[qt][kk] = *(const bf16x8*)(qrow + kk * 16 + hi * 8);
  }

  float lsum[2] = {0.f, 0.f};
  f32x16 o[2][2];  // [qt][dh]: O^T row d=32*dh+(r&3)+8*(r>>2)+4*hi, col q=ql
#pragma unroll
  for (int qt = 0; qt < 2; ++qt)
#pragma unroll
    for (int dh = 0; dh < 2; ++dh) o[qt][dh] = zero16();

  // Staging (T14 reg-staged; split over 8 waves):
  int srow = lane >> 2;
  int schunk = (((lane & 3) ^ ((lane >> 3) & 3)) * 8);
  int kk_w = wave & 1;
  int rb = wave >> 1;      // 0..3
  int stg_row = rb * 16 + srow;
  int rkey = ((lane & 15) >> 1) & 3;  // read-side swizzle key (row%16 == lane&15)

  const u16* gK = Kp + (size_t)stg_row * 1024 + kk_w * 32 + schunk;  // +s0*1024
  const u16* gV = Vp + wave * 512 + lane * 8;                        // +s0*64
  u16* wK = lK[kk_w] + rb * 512 + lane * 8;  // lane's 16B at base+lane*16 (u16*8)
  u16* wV = lV + wave * 512 + lane * 8;

  // prologue: tile 0 regs -> LDS
  i32x4 ldK = *(const i32x4*)gK;
  i32x4 ldV = *(const i32x4*)gV;
  *(i32x4*)wK = ldK;
  *(i32x4*)wV = ldV;
  __syncthreads();

  for (int s0 = 0; s0 < 2048; s0 += 64) {
    bool more = (s0 + 64 < 2048);  // wave-uniform
    if (more) {
      // issue t+1 loads now; latency hides under compute(t)
      ldK = *(const i32x4*)(gK + (size_t)(s0 + 64) * 1024);
      ldV = *(const i32x4*)(gV + (size_t)(s0 + 64) * 64);
    }

#pragma unroll
    for (int sb = 0; sb < 2; ++sb) {
      // K A-fragments (read once, feed both q-tiles):
      bf16x8 kf[4];
      int krb = (sb * 32 + ql) * 32;  // row base (u16)
#pragma unroll
      for (int kk = 0; kk < 4; ++kk)
        kf[kk] = *(const bf16x8*)(lK[kk >> 1] + krb + ((((kk & 1) << 1) | hi) ^ rkey) * 8);

      f32x16 sa0 = zero16(), sa1 = zero16();
#pragma unroll
      for (int kk = 0; kk < 4; ++kk) {
        sa0 = __builtin_amdgcn_mfma_f32_32x32x16_bf16(kf[kk], qf[0][kk], sa0, 0, 0, 0);
        sa1 = __builtin_amdgcn_mfma_f32_32x32x16_bf16(kf[kk], qf[1][kk], sa1, 0, 0, 0);
      }

      // softmax (fixed max 0, log2 units): reg r -> s_local = (r&3)+8*(r>>2)+4*hi
      bf16x8 pu[2][2];
#pragma unroll
      for (int qt = 0; qt < 2; ++qt) {
        float p[16];
#pragma unroll
        for (int r = 0; r < 16; ++r)
          p[r] = exp2_fast(qt == 0 ? sa0[r] : sa1[r]);
        float a0 = (p[0] + p[1]) + (p[2] + p[3]);
        float a1 = (p[4] + p[5]) + (p[6] + p[7]);
        float a2 = (p[8] + p[9]) + (p[10] + p[11]);
        float a3 = (p[12] + p[13]) + (p[14] + p[15]);
        lsum[qt] += (a0 + a1) + (a2 + a3);
#pragma unroll
        for (int ss = 0; ss < 2; ++ss) {
          union { u32 w[4]; bf16x8 v; } pk_;
          pk_.w[0] = pk2(p[8 * ss + 0], p[8 * ss + 1]);
          pk_.w[1] = pk2(p[8 * ss + 2], p[8 * ss + 3]);
          pk_.w[2] = pk2(p[8 * ss + 4], p[8 * ss + 5]);
          pk_.w[3] = pk2(p[8 * ss + 6], p[8 * ss + 7]);
          pu[qt][ss] = pk_.v;
        }
      }

      // PV: per 16-s slice ss, per d-half dh: ONE b128 A-frag read from the
      // fragment-direct image (pi-order k-slots match register-native P).
#pragma unroll
      for (int ss = 0; ss < 2; ++ss) {
        int vbase = (sb * 2 + ss) * 1024 + hi * 512 + ql * 8;
#pragma unroll
        for (int dh = 0; dh < 2; ++dh) {
          bf16x8 vf = *(const bf16x8*)(lV + vbase + dh * 256);
          o[0][dh] = __builtin_amdgcn_mfma_f32_32x32x16_bf16(vf, pu[0][ss], o[0][dh], 0, 0, 0);
          o[1][dh] = __builtin_amdgcn_mfma_f32_32x32x16_bf16(vf, pu[1][ss], o[1][dh], 0, 0, 0);
        }
      }
    }

    __syncthreads();   // all waves done reading tile t; t+1 loads retired
    if (more) {
      *(i32x4*)wK = ldK;
      *(i32x4*)wV = ldV;
    }
    __syncthreads();   // t+1 LDS writes visible
  }

  // epilogue: lsum pairs live on lanes l and l^32 (same q) -> one shfl_xor;
  // normalize, write ctx[b][q][h][d], d = 32*dh + 8*(r>>2) + 4*hi + (r&3)
#pragma unroll
  for (int qt = 0; qt < 2; ++qt) {
    float rs = lsum[qt] + __shfl_xor(lsum[qt], 32);
    float inv = 1.0f / fmaxf(rs, 1e-30f);
    int q = q0 + wave * 64 + qt * 32 + ql;
    size_t rowbase = ((size_t)(b * 2048 + q) * 16 + h) * 64;
#pragma unroll
    for (int dh = 0; dh < 2; ++dh)
#pragma unroll
      for (int rr = 0; rr < 4; ++rr) {
        ushort4 pk;
        pk.x = f2bf_fast(o[qt][dh][4 * rr + 0] * inv);
        pk.y = f2bf_fast(o[qt][dh][4 * rr + 1] * inv);
        pk.z = f2bf_fast(o[qt][dh][4 * rr + 2] * inv);
        pk.w = f2bf_fast(o[qt][dh][4 * rr + 3] * inv);
        *(ushort4*)(ctx + rowbase + dh * 32 + rr * 8 + hi * 4) = pk;
      }
  }
}

// ---------------------------------------------------------------------------
extern "C" void kernel_launch(void* const* d_in, const int* in_sizes, int n_in,
                              void* d_out, int out_size, void* d_ws, size_t ws_size,
                              hipStream_t stream) {
  const float* x  = (const float*)d_in[0];
  const float* wq = (const float*)d_in[1];
  const float* bq = (const float*)d_in[2];
  const float* wk = (const float*)d_in[3];
  const float* bk = (const float*)d_in[4];
  const float* wv = (const float*)d_in[5];
  const float* bv = (const float*)d_in[6];
  const float* wo = (const float*)d_in[7];
  const float* bo = (const float*)d_in[8];

  u16* ws = (u16*)d_ws;
  u16* xb     = ws;                            // 8192*1024 bf16 (16MB)
  u16* wt_qkv = xb + (size_t)8192 * 1024;      // 3072*1024 (6MB)
  u16* wt_o   = wt_qkv + (size_t)3072 * 1024;  // 1024*1024 (2MB)
  u16* Qb     = wt_o + (size_t)1024 * 1024;    // row-major [B,S,D] (16MB)
  u16* Kbuf   = Qb + (size_t)8192 * 1024;      // row-major [B,S,D] (16MB)
  u16* Vgb    = Kbuf + (size_t)8192 * 1024;    // fragment-direct image (16MB)
  u16* ctx    = Vgb + (size_t)8192 * 1024;     // [B,S,D] bf16 (16MB)
  // total ws use: 88MB

  prep<<<9216, 256, 0, stream>>>(x, xb, wq, wk, wv, wo, wt_qkv, wt_o);
  gemm_qkv<<<1536, 256, 0, stream>>>(xb, wt_qkv, bq, bk, bv, Qb, Kbuf, Vgb);
  flash_attn<<<256, 512, 0, stream>>>(Qb, Kbuf, Vgb, ctx);
  gemm_out<<<512, 256, 0, stream>>>(ctx, wt_o, bo, (float*)d_out);
}